// Round 4
// baseline (2772.354 us; speedup 1.0000x reference)
//
#include <hip/hip_runtime.h>
#include <hip/hip_bf16.h>
#include <math.h>

#define HIDDEN 2048
#define HEADS 16
#define HEAD_DIM 128
#define LATENT 512
#define SEQ 2048
#define BATCH 2
#define MROWS (BATCH*SEQ)
#define ATTN_SCALE 0.08838834764831845f  // 1/sqrt(128)

typedef unsigned short u16;
typedef __hip_bfloat16 bf16;

__device__ inline float bf2f(u16 u) { return __uint_as_float(((unsigned)u) << 16); }
__device__ inline float4 ld4(const float* p) { return *(const float4*)p; }
__device__ inline float4 ld4(const bf16* p) {
    ushort4 u = *(const ushort4*)p;
    return make_float4(bf2f(u.x), bf2f(u.y), bf2f(u.z), bf2f(u.w));
}

// ---------------- RoPE cos/sin tables: (SEQ, 32) each, fp32 ----------------
__global__ void rope_table_kernel(float* __restrict__ cosT, float* __restrict__ sinT) {
    int gid = blockIdx.x * blockDim.x + threadIdx.x;
    if (gid >= SEQ * 32) return;
    int t = gid >> 5, j = gid & 31;
    float inv = powf(10000.0f, -(float)j * (1.0f / 32.0f));
    float ang = (float)t * inv;
    cosT[gid] = cosf(ang);
    sinT[gid] = sinf(ang);
}

// ---------------- SGEMM: dst = A(MxK) @ W(KxN) + bias, scatter per MODE ----------------
// A: fp32 (x) or bf16 (intermediates); W, bias: fp32; accumulate fp32.
// MODE 0: bf16 plain dst[m*N+n]
// MODE 1: bf16 q-scatter  (B,H,S,128) lo-half, HD=64
// MODE 2: bf16 k-scatter  (B,H,128,S) lo-half, HD=64
// MODE 3: bf16 v-scatter  (B,H,S,128), HD=128
// MODE 4: fp32 plain dst[m*N+n]   <-- final output (d_out is float*)
template<int MODE, typename TA>
__global__ __launch_bounds__(256) void sgemm_kernel(
    const TA* __restrict__ A, const float* __restrict__ W,
    const float* __restrict__ bias, void* __restrict__ dstv,
    int M, int N, int K)
{
    constexpr int BM = 128, BN = 64, BK = 16, TM = 8, TN = 4;
    __shared__ float As[BK][BM + 4];
    __shared__ float Bs[BK][BN];
    const int tid = threadIdx.x;
    const int mIdx = tid >> 4;      // 0..15
    const int nIdx = tid & 15;      // 0..15
    const int bm = blockIdx.y * BM, bn = blockIdx.x * BN;

    float acc[TM][TN];
#pragma unroll
    for (int i = 0; i < TM; i++)
#pragma unroll
        for (int j = 0; j < TN; j++) acc[i][j] = 0.0f;

    for (int kk = 0; kk < K; kk += BK) {
        // A tile: 128x16, transposed into As[k][m]
#pragma unroll
        for (int i = 0; i < 2; i++) {
            int lin = tid + i * 256;          // 0..511 quads
            int row = lin >> 2;
            int c4 = (lin & 3) << 2;
            float4 a = ld4(A + (size_t)(bm + row) * K + kk + c4);
            As[c4 + 0][row] = a.x; As[c4 + 1][row] = a.y;
            As[c4 + 2][row] = a.z; As[c4 + 3][row] = a.w;
        }
        // B tile: 16x64
        {
            int row = tid >> 4;
            int c4 = (tid & 15) << 2;
            *(float4*)&Bs[row][c4] = ld4(W + (size_t)(kk + row) * N + bn + c4);
        }
        __syncthreads();
#pragma unroll
        for (int k = 0; k < BK; k++) {
            float4 b4 = *(float4*)&Bs[k][nIdx * TN];
            float4 a0 = *(float4*)&As[k][mIdx * TM];
            float4 a1 = *(float4*)&As[k][mIdx * TM + 4];
            float av[8] = {a0.x, a0.y, a0.z, a0.w, a1.x, a1.y, a1.z, a1.w};
            float bv[4] = {b4.x, b4.y, b4.z, b4.w};
#pragma unroll
            for (int i = 0; i < 8; i++)
#pragma unroll
                for (int j = 0; j < 4; j++)
                    acc[i][j] = fmaf(av[i], bv[j], acc[i][j]);
        }
        __syncthreads();
    }

    bf16* dst = (bf16*)dstv;
#pragma unroll
    for (int i = 0; i < TM; i++) {
        int m = bm + mIdx * TM + i;
        int bb = m >> 11;          // / SEQ
        int s = m & 2047;
#pragma unroll
        for (int j = 0; j < TN; j++) {
            int n = bn + nIdx * TN + j;
            float val = acc[i][j] + bias[n];
            if constexpr (MODE == 0) {
                dst[(size_t)m * N + n] = __float2bfloat16(val);
            } else if constexpr (MODE == 1) {
                int h = n >> 6, d = n & 63;
                dst[((size_t)(bb * HEADS + h) * SEQ + s) * HEAD_DIM + d] = __float2bfloat16(val);
            } else if constexpr (MODE == 2) {
                int h = n >> 6, d = n & 63;
                dst[((size_t)(bb * HEADS + h) * HEAD_DIM + d) * SEQ + s] = __float2bfloat16(val);
            } else if constexpr (MODE == 3) {
                int h = n >> 7, d = n & 127;
                dst[((size_t)(bb * HEADS + h) * SEQ + s) * HEAD_DIM + d] = __float2bfloat16(val);
            } else {
                ((float*)dstv)[(size_t)m * N + n] = val;   // fp32 final output
            }
        }
    }
}

// ---------------- RoPE for q2: pointwise, writes hi half of q (B,H,S,128) ----------------
__global__ __launch_bounds__(256) void rope_q_kernel(
    const bf16* __restrict__ t2, const float* __restrict__ cosT,
    const float* __restrict__ sinT, bf16* __restrict__ qg)
{
    int gid = blockIdx.x * blockDim.x + threadIdx.x;   // B*H*S*32 = 2^21
    int j = gid & 31;
    int s = (gid >> 5) & 2047;
    int h = (gid >> 16) & 15;
    int b = gid >> 20;
    const bf16* row = t2 + ((size_t)(b * SEQ + s) * HEADS + h) * 64;
    float rot = bf2f(((const u16*)row)[j]);
    float pas = bf2f(((const u16*)row)[j + 32]);
    float c = cosT[s * 32 + j], sn = sinT[s * 32 + j];
    bf16* o = qg + ((size_t)(b * HEADS + h) * SEQ + s) * HEAD_DIM + 64;
    o[j] = __float2bfloat16(rot * c - pas * sn);
    o[j + 32] = __float2bfloat16(rot * sn + pas * c);
}

// ---------------- RoPE for k2: LDS transpose, writes hi half of k (B,H,128,S) ----------------
__global__ __launch_bounds__(256) void rope_k_kernel(
    const bf16* __restrict__ t2, const float* __restrict__ cosT,
    const float* __restrict__ sinT, bf16* __restrict__ kg)
{
    int st = blockIdx.x * 64, h = blockIdx.y, b = blockIdx.z;
    __shared__ float Rs[64][65];
    const int tid = threadIdx.x;
#pragma unroll
    for (int i = 0; i < 8; i++) {
        int lin = tid + i * 256;      // 0..2047 : 64 s x 32 j
        int s = lin >> 5;
        int j = lin & 31;
        const u16* row = (const u16*)(t2 + ((size_t)(b * SEQ + st + s) * HEADS + h) * 64);
        float rot = bf2f(row[j]), pas = bf2f(row[j + 32]);
        float c = cosT[(st + s) * 32 + j], sn = sinT[(st + s) * 32 + j];
        Rs[s][j] = rot * c - pas * sn;
        Rs[s][j + 32] = rot * sn + pas * c;
    }
    __syncthreads();
#pragma unroll
    for (int i = 0; i < 16; i++) {
        int lin = tid + i * 256;      // 0..4095 : 64 jj x 64 s
        int jj = lin >> 6;
        int s = lin & 63;
        kg[((size_t)(b * HEADS + h) * HEAD_DIM + 64 + jj) * SEQ + st + s] = __float2bfloat16(Rs[s][jj]);
    }
}

// ---------------- causal flash attention; bf16 in, fp32 compute, bf16 out ----------------
// q,v: (B,H,S,128); k: (B,H,128,S); out: (B,S,H*128)
__global__ __launch_bounds__(512) void attn_kernel(
    const bf16* __restrict__ qg, const bf16* __restrict__ kg,
    const bf16* __restrict__ vg, bf16* __restrict__ outp)
{
    const int qt = blockIdx.x, h = blockIdx.y, b = blockIdx.z;
    const int tid = threadIdx.x;
    const bf16* Q = qg + (size_t)(b * HEADS + h) * SEQ * HEAD_DIM;
    const bf16* Kt = kg + (size_t)(b * HEADS + h) * HEAD_DIM * SEQ;
    const bf16* V = vg + (size_t)(b * HEADS + h) * SEQ * HEAD_DIM;

    __shared__ float Qs[64][132];
    __shared__ float KsT[128][68];
    __shared__ float Vs[64][132];
    __shared__ float Ps[64][68];

    const int ri = tid >> 4;        // 0..31
    const int ci = tid & 15;        // 0..15
    const int r0 = ri * 2;
    const int q0 = qt * 64;

    float O[2][8];
#pragma unroll
    for (int j = 0; j < 2; j++)
#pragma unroll
        for (int c = 0; c < 8; c++) O[j][c] = 0.0f;
    float mrow[2] = {-INFINITY, -INFINITY};
    float lrow[2] = {0.0f, 0.0f};

    // load Q tile (64 x 128)
#pragma unroll
    for (int i = 0; i < 4; i++) {
        int lin = tid + i * 512;
        int row = lin >> 5;
        int c4 = (lin & 31) << 2;
        *(float4*)&Qs[row][c4] = ld4(Q + (size_t)(q0 + row) * HEAD_DIM + c4);
    }

    for (int kt = 0; kt <= qt; kt++) {
        __syncthreads();   // protects Qs (first iter) and prev-iter Vs/Ps reads
        // K tile transposed (128 x 64) — global layout already (D,S): coalesced
#pragma unroll
        for (int i = 0; i < 4; i++) {
            int lin = tid + i * 512;
            int d = lin >> 4;
            int j4 = (lin & 15) << 2;
            *(float4*)&KsT[d][j4] = ld4(Kt + (size_t)d * SEQ + kt * 64 + j4);
        }
        // V tile (64 x 128)
#pragma unroll
        for (int i = 0; i < 4; i++) {
            int lin = tid + i * 512;
            int row = lin >> 5;
            int c4 = (lin & 31) << 2;
            *(float4*)&Vs[row][c4] = ld4(V + (size_t)(kt * 64 + row) * HEAD_DIM + c4);
        }
        __syncthreads();

        // QK^T: each thread rows r0..r0+1, cols ci*4..ci*4+3
        float sc0[4] = {0, 0, 0, 0}, sc1[4] = {0, 0, 0, 0};
        for (int kk = 0; kk < 128; kk += 4) {
            float4 qv0 = *(float4*)&Qs[r0][kk];
            float4 qv1 = *(float4*)&Qs[r0 + 1][kk];
            float qa0[4] = {qv0.x, qv0.y, qv0.z, qv0.w};
            float qa1[4] = {qv1.x, qv1.y, qv1.z, qv1.w};
#pragma unroll
            for (int t = 0; t < 4; t++) {
                float4 kb = *(float4*)&KsT[kk + t][ci * 4];
                sc0[0] = fmaf(qa0[t], kb.x, sc0[0]);
                sc0[1] = fmaf(qa0[t], kb.y, sc0[1]);
                sc0[2] = fmaf(qa0[t], kb.z, sc0[2]);
                sc0[3] = fmaf(qa0[t], kb.w, sc0[3]);
                sc1[0] = fmaf(qa1[t], kb.x, sc1[0]);
                sc1[1] = fmaf(qa1[t], kb.y, sc1[1]);
                sc1[2] = fmaf(qa1[t], kb.z, sc1[2]);
                sc1[3] = fmaf(qa1[t], kb.w, sc1[3]);
            }
        }

        // scale + causal mask
        const bool diag = (kt == qt);
#pragma unroll
        for (int jj = 0; jj < 4; jj++) {
            float v0 = sc0[jj] * ATTN_SCALE;
            float v1 = sc1[jj] * ATTN_SCALE;
            if (diag) {
                int kcol = kt * 64 + ci * 4 + jj;
                if (kcol > q0 + r0) v0 = -INFINITY;
                if (kcol > q0 + r0 + 1) v1 = -INFINITY;
            }
            sc0[jj] = v0; sc1[jj] = v1;
        }

        // online softmax across the 16-lane row group
        float t0 = fmaxf(fmaxf(sc0[0], sc0[1]), fmaxf(sc0[2], sc0[3]));
        float t1 = fmaxf(fmaxf(sc1[0], sc1[1]), fmaxf(sc1[2], sc1[3]));
#pragma unroll
        for (int mk = 1; mk < 16; mk <<= 1) {
            t0 = fmaxf(t0, __shfl_xor(t0, mk));
            t1 = fmaxf(t1, __shfl_xor(t1, mk));
        }
        float mn0 = fmaxf(mrow[0], t0), mn1 = fmaxf(mrow[1], t1);
        float rs0 = expf(mrow[0] - mn0), rs1 = expf(mrow[1] - mn1);
        mrow[0] = mn0; mrow[1] = mn1;
        float s0 = 0.0f, s1 = 0.0f;
#pragma unroll
        for (int jj = 0; jj < 4; jj++) {
            sc0[jj] = expf(sc0[jj] - mn0); s0 += sc0[jj];
            sc1[jj] = expf(sc1[jj] - mn1); s1 += sc1[jj];
        }
#pragma unroll
        for (int mk = 1; mk < 16; mk <<= 1) {
            s0 += __shfl_xor(s0, mk);
            s1 += __shfl_xor(s1, mk);
        }
        lrow[0] = lrow[0] * rs0 + s0;
        lrow[1] = lrow[1] * rs1 + s1;
#pragma unroll
        for (int c = 0; c < 8; c++) { O[0][c] *= rs0; O[1][c] *= rs1; }
        *(float4*)&Ps[r0][ci * 4] = make_float4(sc0[0], sc0[1], sc0[2], sc0[3]);
        *(float4*)&Ps[r0 + 1][ci * 4] = make_float4(sc1[0], sc1[1], sc1[2], sc1[3]);
        __syncthreads();

        // PV: thread rows r0..r0+1, cols ci*8..ci*8+7
        for (int kk = 0; kk < 64; kk++) {
            float4 v0 = *(float4*)&Vs[kk][ci * 8];
            float4 v1 = *(float4*)&Vs[kk][ci * 8 + 4];
            float pa = Ps[r0][kk], pb = Ps[r0 + 1][kk];
            O[0][0] = fmaf(pa, v0.x, O[0][0]); O[0][1] = fmaf(pa, v0.y, O[0][1]);
            O[0][2] = fmaf(pa, v0.z, O[0][2]); O[0][3] = fmaf(pa, v0.w, O[0][3]);
            O[0][4] = fmaf(pa, v1.x, O[0][4]); O[0][5] = fmaf(pa, v1.y, O[0][5]);
            O[0][6] = fmaf(pa, v1.z, O[0][6]); O[0][7] = fmaf(pa, v1.w, O[0][7]);
            O[1][0] = fmaf(pb, v0.x, O[1][0]); O[1][1] = fmaf(pb, v0.y, O[1][1]);
            O[1][2] = fmaf(pb, v0.z, O[1][2]); O[1][3] = fmaf(pb, v0.w, O[1][3]);
            O[1][4] = fmaf(pb, v1.x, O[1][4]); O[1][5] = fmaf(pb, v1.y, O[1][5]);
            O[1][6] = fmaf(pb, v1.z, O[1][6]); O[1][7] = fmaf(pb, v1.w, O[1][7]);
        }
    }

    // epilogue: out[(b*S + s)*2048 + h*128 + d], bf16 intermediate
#pragma unroll
    for (int j = 0; j < 2; j++) {
        float inv = 1.0f / lrow[j];
        bf16* dst = outp + ((size_t)(b * SEQ) + q0 + r0 + j) * HIDDEN + h * HEAD_DIM + ci * 8;
#pragma unroll
        for (int c = 0; c < 8; c++) dst[c] = __float2bfloat16(O[j][c] * inv);
    }
}

extern "C" void kernel_launch(void* const* d_in, const int* in_sizes, int n_in,
                              void* d_out, int out_size, void* d_ws, size_t ws_size,
                              hipStream_t stream)
{
    const float* x      = (const float*)d_in[0];
    // d_in[1] = attention_mask (int32 causal tril) — causality implemented directly
    const float* W_kv_d = (const float*)d_in[2];
    const float* b_kv_d = (const float*)d_in[3];
    const float* W_q_d  = (const float*)d_in[4];
    const float* b_q_d  = (const float*)d_in[5];
    const float* W_k_u  = (const float*)d_in[6];
    const float* b_k_u  = (const float*)d_in[7];
    const float* W_q_u  = (const float*)d_in[8];
    const float* b_q_u  = (const float*)d_in[9];
    const float* W_v_u  = (const float*)d_in[10];
    const float* b_v_u  = (const float*)d_in[11];
    const float* W_rk   = (const float*)d_in[12];
    const float* b_rk   = (const float*)d_in[13];
    const float* W_rq   = (const float*)d_in[14];
    const float* b_rq   = (const float*)d_in[15];
    const float* W_o    = (const float*)d_in[16];
    const float* b_o    = (const float*)d_in[17];

    // ---- workspace layout: ~76.0 MB total ----
    float* cosT = (float*)d_ws;                       // 65536 f
    float* sinT = cosT + SEQ * 32;                    // 65536 f
    bf16* kv_d  = (bf16*)(sinT + SEQ * 32);           // 2,097,152 el
    bf16* q_d   = kv_d + (size_t)MROWS * LATENT;      // 2,097,152 el
    bf16* qg    = q_d + (size_t)MROWS * LATENT;       // 8,388,608 el
    bf16* kg    = qg + (size_t)BATCH * HEADS * SEQ * HEAD_DIM;
    bf16* vg    = kg + (size_t)BATCH * HEADS * SEQ * HEAD_DIM;
    bf16* attnb = vg + (size_t)BATCH * HEADS * SEQ * HEAD_DIM;  // 8,388,608 el
    bf16* t2    = attnb;  // alias: t2 (4,194,304 el) dies before attnb is written

    rope_table_kernel<<<(SEQ * 32 + 255) / 256, 256, 0, stream>>>(cosT, sinT);

    // kv_d = x @ W_kv_d + b   (4096 x 512, K=2048)
    sgemm_kernel<0><<<dim3(LATENT / 64, MROWS / 128), 256, 0, stream>>>(x, W_kv_d, b_kv_d, kv_d, MROWS, LATENT, HIDDEN);
    // q_d = x @ W_q_d + b
    sgemm_kernel<0><<<dim3(LATENT / 64, MROWS / 128), 256, 0, stream>>>(x, W_q_d, b_q_d, q_d, MROWS, LATENT, HIDDEN);
    // k1 -> kg lo-half (B,H,128,S)   (4096 x 1024, K=512)
    sgemm_kernel<2><<<dim3(1024 / 64, MROWS / 128), 256, 0, stream>>>(kv_d, W_k_u, b_k_u, kg, MROWS, 1024, LATENT);
    // q1 -> qg lo-half (B,H,S,128)
    sgemm_kernel<1><<<dim3(1024 / 64, MROWS / 128), 256, 0, stream>>>(q_d, W_q_u, b_q_u, qg, MROWS, 1024, LATENT);
    // v -> vg (B,H,S,128)            (4096 x 2048, K=512)
    sgemm_kernel<3><<<dim3(HIDDEN / 64, MROWS / 128), 256, 0, stream>>>(kv_d, W_v_u, b_v_u, vg, MROWS, HIDDEN, LATENT);
    // k2 = x @ W_rk + b -> t2        (4096 x 1024, K=2048)
    sgemm_kernel<0><<<dim3(1024 / 64, MROWS / 128), 256, 0, stream>>>(x, W_rk, b_rk, t2, MROWS, 1024, HIDDEN);
    rope_k_kernel<<<dim3(SEQ / 64, HEADS, BATCH), 256, 0, stream>>>(t2, cosT, sinT, kg);
    // q2 = q_d @ W_rq + b -> t2      (4096 x 1024, K=512)
    sgemm_kernel<0><<<dim3(1024 / 64, MROWS / 128), 256, 0, stream>>>(q_d, W_rq, b_rq, t2, MROWS, 1024, LATENT);
    rope_q_kernel<<<(BATCH * HEADS * SEQ * 32) / 256, 256, 0, stream>>>(t2, cosT, sinT, qg);

    // attention -> attnb (overwrites the t2 alias region; t2 is dead here)
    attn_kernel<<<dim3(SEQ / 64, HEADS, BATCH), 512, 0, stream>>>(qg, kg, vg, attnb);

    // out = attnb @ W_o + b_o -> fp32 d_out   (4096 x 2048, K=2048)
    sgemm_kernel<4><<<dim3(HIDDEN / 64, MROWS / 128), 256, 0, stream>>>(attnb, W_o, b_o, d_out, MROWS, HIDDEN, HIDDEN);
}

// Round 5
// 1665.024 us; speedup vs baseline: 1.6651x; 1.6651x over previous
//
#include <hip/hip_runtime.h>
#include <hip/hip_bf16.h>
#include <math.h>

#define HIDDEN 2048
#define HEADS 16
#define HEAD_DIM 128
#define LATENT 512
#define SEQ 2048
#define BATCH 2
#define MROWS (BATCH*SEQ)
#define ATTN_SCALE 0.08838834764831845f  // 1/sqrt(128)

typedef unsigned short u16;
typedef __hip_bfloat16 bf16;
typedef __attribute__((ext_vector_type(8))) short bf16x8;
typedef __attribute__((ext_vector_type(4))) float f32x4;

__device__ inline float bf2f(u16 u) { return __uint_as_float(((unsigned)u) << 16); }
__device__ inline float4 ld4(const float* p) { return *(const float4*)p; }
__device__ inline float4 ld4(const bf16* p) {
    ushort4 u = *(const ushort4*)p;
    return make_float4(bf2f(u.x), bf2f(u.y), bf2f(u.z), bf2f(u.w));
}

// ---------------- RoPE cos/sin tables: (SEQ, 32) each, fp32 ----------------
__global__ void rope_table_kernel(float* __restrict__ cosT, float* __restrict__ sinT) {
    int gid = blockIdx.x * blockDim.x + threadIdx.x;
    if (gid >= SEQ * 32) return;
    int t = gid >> 5, j = gid & 31;
    float inv = powf(10000.0f, -(float)j * (1.0f / 32.0f));
    float ang = (float)t * inv;
    cosT[gid] = cosf(ang);
    sinT[gid] = sinf(ang);
}

// ---------------- cast x (M,K fp32) -> xb (M,K bf16) ----------------
__global__ __launch_bounds__(256) void castx_kernel(const float* __restrict__ x, bf16* __restrict__ xb) {
    size_t gid = (size_t)blockIdx.x * 256 + threadIdx.x;   // 8 elems per thread
    const float* p = x + gid * 8;
    float4 a = *(const float4*)p;
    float4 b = *(const float4*)(p + 4);
    bf16 o[8] = {__float2bfloat16(a.x), __float2bfloat16(a.y), __float2bfloat16(a.z), __float2bfloat16(a.w),
                 __float2bfloat16(b.x), __float2bfloat16(b.y), __float2bfloat16(b.z), __float2bfloat16(b.w)};
    *(uint4*)(xb + gid * 8) = *(uint4*)o;
}

// ---------------- transpose-cast W (K,N fp32) -> Wt (N,K bf16) ----------------
__global__ __launch_bounds__(256) void tcast_kernel(const float* __restrict__ W, bf16* __restrict__ Wt,
                                                    int K, int N) {
    __shared__ float T[32][33];
    int k0 = blockIdx.x * 32, n0 = blockIdx.y * 32;
    int tx = threadIdx.x & 31, ty = threadIdx.x >> 5;   // ty 0..7
#pragma unroll
    for (int p = 0; p < 4; p++) {
        int kr = p * 8 + ty;
        T[kr][tx] = W[(size_t)(k0 + kr) * N + n0 + tx];
    }
    __syncthreads();
#pragma unroll
    for (int p = 0; p < 4; p++) {
        int nr = p * 8 + ty;
        Wt[(size_t)(n0 + nr) * K + k0 + tx] = __float2bfloat16(T[tx][nr]);
    }
}

// ---------------- MFMA GEMM: dst = A(MxK,bf16) @ Wt^T(N,K,bf16) + bias(fp32) ----------------
// MODE 0: bf16 plain dst[m*N+n]
// MODE 1: bf16 q-scatter  (B,H,S,128) lo-half, HD=64
// MODE 2: bf16 k-scatter  (B,H,128,S) lo-half, HD=64
// MODE 3: bf16 v-scatter  (B,H,S,128), HD=128
// MODE 4: fp32 plain dst[m*N+n]
template<int MODE>
__global__ __launch_bounds__(256) void mfma_gemm(
    const bf16* __restrict__ A, const bf16* __restrict__ Bt,
    const float* __restrict__ bias, void* __restrict__ dstv,
    int M, int N, int K)
{
    constexpr int BM = 128, BN = 128, BK = 32;
    constexpr int LDT = BK + 8;                 // 40 shorts = 80 B padded row (16B aligned)
    __shared__ short As[2][BM * LDT];
    __shared__ short Bs[2][BN * LDT];

    const int tid = threadIdx.x;
    const int wid = tid >> 6;                   // wave 0..3
    const int lane = tid & 63;
    const int wm = (wid >> 1) * 64;             // wave output offset in tile
    const int wn = (wid & 1) * 64;
    const int bm = blockIdx.y * BM, bn = blockIdx.x * BN;

    // staging: thread covers row tid>>1, 16-element half (tid&1) of the 32-wide K slice
    const int srow = tid >> 1;
    const int soff = (tid & 1) * 16;
    const bf16* Aptr = A + (size_t)(bm + srow) * K + soff;
    const bf16* Bptr = Bt + (size_t)(bn + srow) * K + soff;
    const int sdst = srow * LDT + soff;

    // fragment indices
    const int fr = lane & 15;                   // row (A) / col (B) within 16
    const int fk = lane >> 4;                   // k-block (8 elements each)

    f32x4 acc[4][4];
#pragma unroll
    for (int mi = 0; mi < 4; mi++)
#pragma unroll
        for (int ni = 0; ni < 4; ni++)
            acc[mi][ni] = (f32x4){0.f, 0.f, 0.f, 0.f};

    // prologue: stage tile 0
    {
        uint4 a0 = *(const uint4*)(Aptr);
        uint4 a1 = *(const uint4*)(Aptr + 8);
        uint4 b0 = *(const uint4*)(Bptr);
        uint4 b1 = *(const uint4*)(Bptr + 8);
        *(uint4*)&As[0][sdst] = a0;
        *(uint4*)&As[0][sdst + 8] = a1;
        *(uint4*)&Bs[0][sdst] = b0;
        *(uint4*)&Bs[0][sdst + 8] = b1;
    }

    const int NT = K / BK;
    int cur = 0;
    for (int t = 0; t < NT; t++) {
        __syncthreads();                        // buf[cur] staged; buf[cur^1] free
        uint4 a0, a1, b0, b1;
        const bool more = (t + 1 < NT);
        if (more) {                             // prefetch next K-slice into regs
            const bf16* ap = Aptr + (size_t)(t + 1) * BK;
            const bf16* bp = Bptr + (size_t)(t + 1) * BK;
            a0 = *(const uint4*)(ap);
            a1 = *(const uint4*)(ap + 8);
            b0 = *(const uint4*)(bp);
            b1 = *(const uint4*)(bp + 8);
        }
        // compute on buf[cur]
        bf16x8 af[4], bfr[4];
#pragma unroll
        for (int mi = 0; mi < 4; mi++)
            af[mi] = *(const bf16x8*)&As[cur][(wm + mi * 16 + fr) * LDT + fk * 8];
#pragma unroll
        for (int ni = 0; ni < 4; ni++)
            bfr[ni] = *(const bf16x8*)&Bs[cur][(wn + ni * 16 + fr) * LDT + fk * 8];
#pragma unroll
        for (int mi = 0; mi < 4; mi++)
#pragma unroll
            for (int ni = 0; ni < 4; ni++)
                acc[mi][ni] = __builtin_amdgcn_mfma_f32_16x16x32_bf16(af[mi], bfr[ni], acc[mi][ni], 0, 0, 0);
        if (more) {
            *(uint4*)&As[cur ^ 1][sdst] = a0;
            *(uint4*)&As[cur ^ 1][sdst + 8] = a1;
            *(uint4*)&Bs[cur ^ 1][sdst] = b0;
            *(uint4*)&Bs[cur ^ 1][sdst + 8] = b1;
            cur ^= 1;
        }
    }

    // epilogue: C/D layout col=lane&15, row=(lane>>4)*4+reg  [m89-verified]
    const int cr = (lane >> 4) * 4;
    bf16* dst = (bf16*)dstv;
#pragma unroll
    for (int mi = 0; mi < 4; mi++) {
#pragma unroll
        for (int j = 0; j < 4; j++) {
            int m = bm + wm + mi * 16 + cr + j;
            int bb = m >> 11;                   // / SEQ
            int s = m & 2047;
#pragma unroll
            for (int ni = 0; ni < 4; ni++) {
                int n = bn + wn + ni * 16 + fr;
                float val = acc[mi][ni][j] + bias[n];
                if constexpr (MODE == 0) {
                    dst[(size_t)m * N + n] = __float2bfloat16(val);
                } else if constexpr (MODE == 1) {
                    int h = n >> 6, d = n & 63;
                    dst[((size_t)(bb * HEADS + h) * SEQ + s) * HEAD_DIM + d] = __float2bfloat16(val);
                } else if constexpr (MODE == 2) {
                    int h = n >> 6, d = n & 63;
                    dst[((size_t)(bb * HEADS + h) * HEAD_DIM + d) * SEQ + s] = __float2bfloat16(val);
                } else if constexpr (MODE == 3) {
                    int h = n >> 7, d = n & 127;
                    dst[((size_t)(bb * HEADS + h) * SEQ + s) * HEAD_DIM + d] = __float2bfloat16(val);
                } else {
                    ((float*)dstv)[(size_t)m * N + n] = val;
                }
            }
        }
    }
}

// ---------------- RoPE for q2: pointwise, writes hi half of q (B,H,S,128) ----------------
__global__ __launch_bounds__(256) void rope_q_kernel(
    const bf16* __restrict__ t2, const float* __restrict__ cosT,
    const float* __restrict__ sinT, bf16* __restrict__ qg)
{
    int gid = blockIdx.x * blockDim.x + threadIdx.x;   // B*H*S*32 = 2^21
    int j = gid & 31;
    int s = (gid >> 5) & 2047;
    int h = (gid >> 16) & 15;
    int b = gid >> 20;
    const bf16* row = t2 + ((size_t)(b * SEQ + s) * HEADS + h) * 64;
    float rot = bf2f(((const u16*)row)[j]);
    float pas = bf2f(((const u16*)row)[j + 32]);
    float c = cosT[s * 32 + j], sn = sinT[s * 32 + j];
    bf16* o = qg + ((size_t)(b * HEADS + h) * SEQ + s) * HEAD_DIM + 64;
    o[j] = __float2bfloat16(rot * c - pas * sn);
    o[j + 32] = __float2bfloat16(rot * sn + pas * c);
}

// ---------------- RoPE for k2: LDS transpose, writes hi half of k (B,H,128,S) ----------------
__global__ __launch_bounds__(256) void rope_k_kernel(
    const bf16* __restrict__ t2, const float* __restrict__ cosT,
    const float* __restrict__ sinT, bf16* __restrict__ kg)
{
    int st = blockIdx.x * 64, h = blockIdx.y, b = blockIdx.z;
    __shared__ float Rs[64][65];
    const int tid = threadIdx.x;
#pragma unroll
    for (int i = 0; i < 8; i++) {
        int lin = tid + i * 256;      // 0..2047 : 64 s x 32 j
        int s = lin >> 5;
        int j = lin & 31;
        const u16* row = (const u16*)(t2 + ((size_t)(b * SEQ + st + s) * HEADS + h) * 64);
        float rot = bf2f(row[j]), pas = bf2f(row[j + 32]);
        float c = cosT[(st + s) * 32 + j], sn = sinT[(st + s) * 32 + j];
        Rs[s][j] = rot * c - pas * sn;
        Rs[s][j + 32] = rot * sn + pas * c;
    }
    __syncthreads();
#pragma unroll
    for (int i = 0; i < 16; i++) {
        int lin = tid + i * 256;      // 0..4095 : 64 jj x 64 s
        int jj = lin >> 6;
        int s = lin & 63;
        kg[((size_t)(b * HEADS + h) * HEAD_DIM + 64 + jj) * SEQ + st + s] = __float2bfloat16(Rs[s][jj]);
    }
}

// ---------------- causal flash attention; bf16 in, fp32 compute, bf16 out ----------------
// q,v: (B,H,S,128); k: (B,H,128,S); out: (B,S,H*128)
__global__ __launch_bounds__(512) void attn_kernel(
    const bf16* __restrict__ qg, const bf16* __restrict__ kg,
    const bf16* __restrict__ vg, bf16* __restrict__ outp)
{
    const int qt = blockIdx.x, h = blockIdx.y, b = blockIdx.z;
    const int tid = threadIdx.x;
    const bf16* Q = qg + (size_t)(b * HEADS + h) * SEQ * HEAD_DIM;
    const bf16* Kt = kg + (size_t)(b * HEADS + h) * HEAD_DIM * SEQ;
    const bf16* V = vg + (size_t)(b * HEADS + h) * SEQ * HEAD_DIM;

    __shared__ float Qs[64][132];
    __shared__ float KsT[128][68];
    __shared__ float Vs[64][132];
    __shared__ float Ps[64][68];

    const int ri = tid >> 4;        // 0..31
    const int ci = tid & 15;        // 0..15
    const int r0 = ri * 2;
    const int q0 = qt * 64;

    float O[2][8];
#pragma unroll
    for (int j = 0; j < 2; j++)
#pragma unroll
        for (int c = 0; c < 8; c++) O[j][c] = 0.0f;
    float mrow[2] = {-INFINITY, -INFINITY};
    float lrow[2] = {0.0f, 0.0f};

    // load Q tile (64 x 128)
#pragma unroll
    for (int i = 0; i < 4; i++) {
        int lin = tid + i * 512;
        int row = lin >> 5;
        int c4 = (lin & 31) << 2;
        *(float4*)&Qs[row][c4] = ld4(Q + (size_t)(q0 + row) * HEAD_DIM + c4);
    }

    for (int kt = 0; kt <= qt; kt++) {
        __syncthreads();
#pragma unroll
        for (int i = 0; i < 4; i++) {
            int lin = tid + i * 512;
            int d = lin >> 4;
            int j4 = (lin & 15) << 2;
            *(float4*)&KsT[d][j4] = ld4(Kt + (size_t)d * SEQ + kt * 64 + j4);
        }
#pragma unroll
        for (int i = 0; i < 4; i++) {
            int lin = tid + i * 512;
            int row = lin >> 5;
            int c4 = (lin & 31) << 2;
            *(float4*)&Vs[row][c4] = ld4(V + (size_t)(kt * 64 + row) * HEAD_DIM + c4);
        }
        __syncthreads();

        float sc0[4] = {0, 0, 0, 0}, sc1[4] = {0, 0, 0, 0};
        for (int kk = 0; kk < 128; kk += 4) {
            float4 qv0 = *(float4*)&Qs[r0][kk];
            float4 qv1 = *(float4*)&Qs[r0 + 1][kk];
            float qa0[4] = {qv0.x, qv0.y, qv0.z, qv0.w};
            float qa1[4] = {qv1.x, qv1.y, qv1.z, qv1.w};
#pragma unroll
            for (int t = 0; t < 4; t++) {
                float4 kb = *(float4*)&KsT[kk + t][ci * 4];
                sc0[0] = fmaf(qa0[t], kb.x, sc0[0]);
                sc0[1] = fmaf(qa0[t], kb.y, sc0[1]);
                sc0[2] = fmaf(qa0[t], kb.z, sc0[2]);
                sc0[3] = fmaf(qa0[t], kb.w, sc0[3]);
                sc1[0] = fmaf(qa1[t], kb.x, sc1[0]);
                sc1[1] = fmaf(qa1[t], kb.y, sc1[1]);
                sc1[2] = fmaf(qa1[t], kb.z, sc1[2]);
                sc1[3] = fmaf(qa1[t], kb.w, sc1[3]);
            }
        }

        const bool diag = (kt == qt);
#pragma unroll
        for (int jj = 0; jj < 4; jj++) {
            float v0 = sc0[jj] * ATTN_SCALE;
            float v1 = sc1[jj] * ATTN_SCALE;
            if (diag) {
                int kcol = kt * 64 + ci * 4 + jj;
                if (kcol > q0 + r0) v0 = -INFINITY;
                if (kcol > q0 + r0 + 1) v1 = -INFINITY;
            }
            sc0[jj] = v0; sc1[jj] = v1;
        }

        float t0 = fmaxf(fmaxf(sc0[0], sc0[1]), fmaxf(sc0[2], sc0[3]));
        float t1 = fmaxf(fmaxf(sc1[0], sc1[1]), fmaxf(sc1[2], sc1[3]));
#pragma unroll
        for (int mk = 1; mk < 16; mk <<= 1) {
            t0 = fmaxf(t0, __shfl_xor(t0, mk));
            t1 = fmaxf(t1, __shfl_xor(t1, mk));
        }
        float mn0 = fmaxf(mrow[0], t0), mn1 = fmaxf(mrow[1], t1);
        float rs0 = expf(mrow[0] - mn0), rs1 = expf(mrow[1] - mn1);
        mrow[0] = mn0; mrow[1] = mn1;
        float s0 = 0.0f, s1 = 0.0f;
#pragma unroll
        for (int jj = 0; jj < 4; jj++) {
            sc0[jj] = expf(sc0[jj] - mn0); s0 += sc0[jj];
            sc1[jj] = expf(sc1[jj] - mn1); s1 += sc1[jj];
        }
#pragma unroll
        for (int mk = 1; mk < 16; mk <<= 1) {
            s0 += __shfl_xor(s0, mk);
            s1 += __shfl_xor(s1, mk);
        }
        lrow[0] = lrow[0] * rs0 + s0;
        lrow[1] = lrow[1] * rs1 + s1;
#pragma unroll
        for (int c = 0; c < 8; c++) { O[0][c] *= rs0; O[1][c] *= rs1; }
        *(float4*)&Ps[r0][ci * 4] = make_float4(sc0[0], sc0[1], sc0[2], sc0[3]);
        *(float4*)&Ps[r0 + 1][ci * 4] = make_float4(sc1[0], sc1[1], sc1[2], sc1[3]);
        __syncthreads();

        for (int kk = 0; kk < 64; kk++) {
            float4 v0 = *(float4*)&Vs[kk][ci * 8];
            float4 v1 = *(float4*)&Vs[kk][ci * 8 + 4];
            float pa = Ps[r0][kk], pb = Ps[r0 + 1][kk];
            O[0][0] = fmaf(pa, v0.x, O[0][0]); O[0][1] = fmaf(pa, v0.y, O[0][1]);
            O[0][2] = fmaf(pa, v0.z, O[0][2]); O[0][3] = fmaf(pa, v0.w, O[0][3]);
            O[0][4] = fmaf(pa, v1.x, O[0][4]); O[0][5] = fmaf(pa, v1.y, O[0][5]);
            O[0][6] = fmaf(pa, v1.z, O[0][6]); O[0][7] = fmaf(pa, v1.w, O[0][7]);
            O[1][0] = fmaf(pb, v0.x, O[1][0]); O[1][1] = fmaf(pb, v0.y, O[1][1]);
            O[1][2] = fmaf(pb, v0.z, O[1][2]); O[1][3] = fmaf(pb, v0.w, O[1][3]);
            O[1][4] = fmaf(pb, v1.x, O[1][4]); O[1][5] = fmaf(pb, v1.y, O[1][5]);
            O[1][6] = fmaf(pb, v1.z, O[1][6]); O[1][7] = fmaf(pb, v1.w, O[1][7]);
        }
    }

#pragma unroll
    for (int j = 0; j < 2; j++) {
        float inv = 1.0f / lrow[j];
        bf16* dst = outp + ((size_t)(b * SEQ) + q0 + r0 + j) * HIDDEN + h * HEAD_DIM + ci * 8;
#pragma unroll
        for (int c = 0; c < 8; c++) dst[c] = __float2bfloat16(O[j][c] * inv);
    }
}

extern "C" void kernel_launch(void* const* d_in, const int* in_sizes, int n_in,
                              void* d_out, int out_size, void* d_ws, size_t ws_size,
                              hipStream_t stream)
{
    const float* x      = (const float*)d_in[0];
    // d_in[1] = attention_mask (int32 causal tril) — causality implemented directly
    const float* W_kv_d = (const float*)d_in[2];
    const float* b_kv_d = (const float*)d_in[3];
    const float* W_q_d  = (const float*)d_in[4];
    const float* b_q_d  = (const float*)d_in[5];
    const float* W_k_u  = (const float*)d_in[6];
    const float* b_k_u  = (const float*)d_in[7];
    const float* W_q_u  = (const float*)d_in[8];
    const float* b_q_u  = (const float*)d_in[9];
    const float* W_v_u  = (const float*)d_in[10];
    const float* b_v_u  = (const float*)d_in[11];
    const float* W_rk   = (const float*)d_in[12];
    const float* b_rk   = (const float*)d_in[13];
    const float* W_rq   = (const float*)d_in[14];
    const float* b_rq   = (const float*)d_in[15];
    const float* W_o    = (const float*)d_in[16];
    const float* b_o    = (const float*)d_in[17];

    // ---- workspace layout (~114 MB) ----
    float* cosT = (float*)d_ws;                       // 65536 f
    float* sinT = cosT + SEQ * 32;                    // 65536 f
    bf16* kv_d  = (bf16*)(sinT + SEQ * 32);           // 4096*512
    bf16* q_d   = kv_d + (size_t)MROWS * LATENT;      // 4096*512
    bf16* qg    = q_d + (size_t)MROWS * LATENT;       // 32*2048*128
    bf16* kg    = qg + (size_t)BATCH * HEADS * SEQ * HEAD_DIM;
    bf16* vg    = kg + (size_t)BATCH * HEADS * SEQ * HEAD_DIM;
    bf16* attnb = vg + (size_t)BATCH * HEADS * SEQ * HEAD_DIM;  // 4096*2048
    bf16* t2    = attnb;                              // alias (dies before attnb written)
    bf16* xb    = attnb + (size_t)MROWS * HIDDEN;     // 4096*2048
    bf16* wt    = xb + (size_t)MROWS * HIDDEN;
    bf16* Wt_kvd = wt;                                // (512,2048)
    bf16* Wt_qd  = Wt_kvd + (size_t)LATENT * HIDDEN;  // (512,2048)
    bf16* Wt_ku  = Wt_qd + (size_t)LATENT * HIDDEN;   // (1024,512)
    bf16* Wt_qu  = Wt_ku + (size_t)1024 * LATENT;     // (1024,512)
    bf16* Wt_vu  = Wt_qu + (size_t)1024 * LATENT;     // (2048,512)
    bf16* Wt_rk  = Wt_vu + (size_t)HIDDEN * LATENT;   // (1024,2048)
    bf16* Wt_rq  = Wt_rk + (size_t)1024 * HIDDEN;     // (1024,512)
    bf16* Wt_o   = Wt_rq + (size_t)1024 * LATENT;     // (2048,2048)

    rope_table_kernel<<<(SEQ * 32 + 255) / 256, 256, 0, stream>>>(cosT, sinT);
    castx_kernel<<<MROWS * HIDDEN / 8 / 256, 256, 0, stream>>>(x, xb);
    tcast_kernel<<<dim3(HIDDEN / 32, LATENT / 32), 256, 0, stream>>>(W_kv_d, Wt_kvd, HIDDEN, LATENT);
    tcast_kernel<<<dim3(HIDDEN / 32, LATENT / 32), 256, 0, stream>>>(W_q_d, Wt_qd, HIDDEN, LATENT);
    tcast_kernel<<<dim3(LATENT / 32, 1024 / 32), 256, 0, stream>>>(W_k_u, Wt_ku, LATENT, 1024);
    tcast_kernel<<<dim3(LATENT / 32, 1024 / 32), 256, 0, stream>>>(W_q_u, Wt_qu, LATENT, 1024);
    tcast_kernel<<<dim3(LATENT / 32, HIDDEN / 32), 256, 0, stream>>>(W_v_u, Wt_vu, LATENT, HIDDEN);
    tcast_kernel<<<dim3(HIDDEN / 32, 1024 / 32), 256, 0, stream>>>(W_rk, Wt_rk, HIDDEN, 1024);
    tcast_kernel<<<dim3(LATENT / 32, 1024 / 32), 256, 0, stream>>>(W_rq, Wt_rq, LATENT, 1024);
    tcast_kernel<<<dim3(HIDDEN / 32, HIDDEN / 32), 256, 0, stream>>>(W_o, Wt_o, HIDDEN, HIDDEN);

    // kv_d = x @ W_kv_d + b   (M=4096, N=512, K=2048)
    mfma_gemm<0><<<dim3(LATENT / 128, MROWS / 128), 256, 0, stream>>>(xb, Wt_kvd, b_kv_d, kv_d, MROWS, LATENT, HIDDEN);
    mfma_gemm<0><<<dim3(LATENT / 128, MROWS / 128), 256, 0, stream>>>(xb, Wt_qd, b_q_d, q_d, MROWS, LATENT, HIDDEN);
    // k1 -> kg lo-half (B,H,128,S)   (N=1024, K=512)
    mfma_gemm<2><<<dim3(1024 / 128, MROWS / 128), 256, 0, stream>>>(kv_d, Wt_ku, b_k_u, kg, MROWS, 1024, LATENT);
    // q1 -> qg lo-half (B,H,S,128)
    mfma_gemm<1><<<dim3(1024 / 128, MROWS / 128), 256, 0, stream>>>(q_d, Wt_qu, b_q_u, qg, MROWS, 1024, LATENT);
    // v -> vg (B,H,S,128)            (N=2048, K=512)
    mfma_gemm<3><<<dim3(HIDDEN / 128, MROWS / 128), 256, 0, stream>>>(kv_d, Wt_vu, b_v_u, vg, MROWS, HIDDEN, LATENT);
    // k2 = x @ W_rk + b -> t2        (N=1024, K=2048)
    mfma_gemm<0><<<dim3(1024 / 128, MROWS / 128), 256, 0, stream>>>(xb, Wt_rk, b_rk, t2, MROWS, 1024, HIDDEN);
    rope_k_kernel<<<dim3(SEQ / 64, HEADS, BATCH), 256, 0, stream>>>(t2, cosT, sinT, kg);
    // q2 = q_d @ W_rq + b -> t2      (N=1024, K=512)
    mfma_gemm<0><<<dim3(1024 / 128, MROWS / 128), 256, 0, stream>>>(q_d, Wt_rq, b_rq, t2, MROWS, 1024, LATENT);
    rope_q_kernel<<<(BATCH * HEADS * SEQ * 32) / 256, 256, 0, stream>>>(t2, cosT, sinT, qg);

    // attention -> attnb
    attn_kernel<<<dim3(SEQ / 64, HEADS, BATCH), 512, 0, stream>>>(qg, kg, vg, attnb);

    // out = attnb @ W_o + b_o -> fp32 d_out   (N=2048, K=2048)
    mfma_gemm<4><<<dim3(HIDDEN / 128, MROWS / 128), 256, 0, stream>>>(attnb, Wt_o, b_o, d_out, MROWS, HIDDEN, HIDDEN);
}

// Round 7
// 441.751 us; speedup vs baseline: 6.2758x; 3.7691x over previous
//
#include <hip/hip_runtime.h>
#include <hip/hip_bf16.h>
#include <math.h>

#define HIDDEN 2048
#define HEADS 16
#define HEAD_DIM 128
#define LATENT 512
#define SEQ 2048
#define BATCH 2
#define MROWS (BATCH*SEQ)
#define ATTN_SCALE 0.08838834764831845f  // 1/sqrt(128)

typedef unsigned short u16;
typedef __hip_bfloat16 bf16;
typedef __attribute__((ext_vector_type(8))) short bf16x8;
typedef __attribute__((ext_vector_type(4))) float f32x4;

__device__ inline float bf2f(u16 u) { return __uint_as_float(((unsigned)u) << 16); }
__device__ inline short f2bf_s(float v) { bf16 t = __float2bfloat16(v); return *(short*)&t; }

// ---------------- RoPE cos/sin tables: (SEQ, 32) each, fp32 ----------------
__global__ void rope_table_kernel(float* __restrict__ cosT, float* __restrict__ sinT) {
    int gid = blockIdx.x * blockDim.x + threadIdx.x;
    if (gid >= SEQ * 32) return;
    int t = gid >> 5, j = gid & 31;
    float inv = powf(10000.0f, -(float)j * (1.0f / 32.0f));
    float ang = (float)t * inv;
    cosT[gid] = cosf(ang);
    sinT[gid] = sinf(ang);
}

// ---------------- cast x (M,K fp32) -> xb (M,K bf16) ----------------
__global__ __launch_bounds__(256) void castx_kernel(const float* __restrict__ x, bf16* __restrict__ xb) {
    size_t gid = (size_t)blockIdx.x * 256 + threadIdx.x;   // 8 elems per thread
    const float* p = x + gid * 8;
    float4 a = *(const float4*)p;
    float4 b = *(const float4*)(p + 4);
    bf16 o[8] = {__float2bfloat16(a.x), __float2bfloat16(a.y), __float2bfloat16(a.z), __float2bfloat16(a.w),
                 __float2bfloat16(b.x), __float2bfloat16(b.y), __float2bfloat16(b.z), __float2bfloat16(b.w)};
    *(uint4*)(xb + gid * 8) = *(uint4*)o;
}

// ---------------- transpose-cast W (K,N fp32) -> Wt (N,K bf16) ----------------
__global__ __launch_bounds__(256) void tcast_kernel(const float* __restrict__ W, bf16* __restrict__ Wt,
                                                    int K, int N) {
    __shared__ float T[32][33];
    int k0 = blockIdx.x * 32, n0 = blockIdx.y * 32;
    int tx = threadIdx.x & 31, ty = threadIdx.x >> 5;   // ty 0..7
#pragma unroll
    for (int p = 0; p < 4; p++) {
        int kr = p * 8 + ty;
        T[kr][tx] = W[(size_t)(k0 + kr) * N + n0 + tx];
    }
    __syncthreads();
#pragma unroll
    for (int p = 0; p < 4; p++) {
        int nr = p * 8 + ty;
        Wt[(size_t)(n0 + nr) * K + k0 + tx] = __float2bfloat16(T[tx][nr]);
    }
}

// ---------------- MFMA GEMM: dst = A(MxK,bf16) @ Wt^T(N,K,bf16) + bias(fp32) ----------------
// MODE 0: bf16 plain dst[m*N+n]
// MODE 1: bf16 qk-scatter (B,H,S,128) lo-half (h=n>>6, d=n&63)
// MODE 2: bf16 v-transpose-scatter (B,H,128,S) (h=n>>7, d=n&127)
// MODE 4: fp32 plain dst[m*N+n]
template<int MODE>
__global__ __launch_bounds__(256) void mfma_gemm(
    const bf16* __restrict__ A, const bf16* __restrict__ Bt,
    const float* __restrict__ bias, void* __restrict__ dstv,
    int M, int N, int K)
{
    constexpr int BM = 128, BN = 128, BK = 32;
    constexpr int LDT = BK + 8;                 // 40 shorts = 80 B padded row
    __shared__ short As[2][BM * LDT];
    __shared__ short Bs[2][BN * LDT];

    const int tid = threadIdx.x;
    const int wid = tid >> 6;                   // wave 0..3
    const int lane = tid & 63;
    const int wm = (wid >> 1) * 64;
    const int wn = (wid & 1) * 64;
    const int bm = blockIdx.y * BM, bn = blockIdx.x * BN;

    const int srow = tid >> 1;
    const int soff = (tid & 1) * 16;
    const bf16* Aptr = A + (size_t)(bm + srow) * K + soff;
    const bf16* Bptr = Bt + (size_t)(bn + srow) * K + soff;
    const int sdst = srow * LDT + soff;

    const int fr = lane & 15;
    const int fk = lane >> 4;

    f32x4 acc[4][4];
#pragma unroll
    for (int mi = 0; mi < 4; mi++)
#pragma unroll
        for (int ni = 0; ni < 4; ni++)
            acc[mi][ni] = (f32x4){0.f, 0.f, 0.f, 0.f};

    {
        uint4 a0 = *(const uint4*)(Aptr);
        uint4 a1 = *(const uint4*)(Aptr + 8);
        uint4 b0 = *(const uint4*)(Bptr);
        uint4 b1 = *(const uint4*)(Bptr + 8);
        *(uint4*)&As[0][sdst] = a0;
        *(uint4*)&As[0][sdst + 8] = a1;
        *(uint4*)&Bs[0][sdst] = b0;
        *(uint4*)&Bs[0][sdst + 8] = b1;
    }

    const int NT = K / BK;
    int cur = 0;
    for (int t = 0; t < NT; t++) {
        __syncthreads();
        uint4 a0, a1, b0, b1;
        const bool more = (t + 1 < NT);
        if (more) {
            const bf16* ap = Aptr + (size_t)(t + 1) * BK;
            const bf16* bp = Bptr + (size_t)(t + 1) * BK;
            a0 = *(const uint4*)(ap);
            a1 = *(const uint4*)(ap + 8);
            b0 = *(const uint4*)(bp);
            b1 = *(const uint4*)(bp + 8);
        }
        bf16x8 af[4], bfr[4];
#pragma unroll
        for (int mi = 0; mi < 4; mi++)
            af[mi] = *(const bf16x8*)&As[cur][(wm + mi * 16 + fr) * LDT + fk * 8];
#pragma unroll
        for (int ni = 0; ni < 4; ni++)
            bfr[ni] = *(const bf16x8*)&Bs[cur][(wn + ni * 16 + fr) * LDT + fk * 8];
#pragma unroll
        for (int mi = 0; mi < 4; mi++)
#pragma unroll
            for (int ni = 0; ni < 4; ni++)
                acc[mi][ni] = __builtin_amdgcn_mfma_f32_16x16x32_bf16(af[mi], bfr[ni], acc[mi][ni], 0, 0, 0);
        if (more) {
            *(uint4*)&As[cur ^ 1][sdst] = a0;
            *(uint4*)&As[cur ^ 1][sdst + 8] = a1;
            *(uint4*)&Bs[cur ^ 1][sdst] = b0;
            *(uint4*)&Bs[cur ^ 1][sdst + 8] = b1;
            cur ^= 1;
        }
    }

    const int cr = (lane >> 4) * 4;
    bf16* dst = (bf16*)dstv;
#pragma unroll
    for (int mi = 0; mi < 4; mi++) {
#pragma unroll
        for (int j = 0; j < 4; j++) {
            int m = bm + wm + mi * 16 + cr + j;
            int bb = m >> 11;                   // / SEQ
            int s = m & 2047;
#pragma unroll
            for (int ni = 0; ni < 4; ni++) {
                int n = bn + wn + ni * 16 + fr;
                float val = acc[mi][ni][j] + bias[n];
                if constexpr (MODE == 0) {
                    dst[(size_t)m * N + n] = __float2bfloat16(val);
                } else if constexpr (MODE == 1) {
                    int h = n >> 6, d = n & 63;
                    dst[((size_t)(bb * HEADS + h) * SEQ + s) * HEAD_DIM + d] = __float2bfloat16(val);
                } else if constexpr (MODE == 2) {
                    int h = n >> 7, d = n & 127;
                    dst[((size_t)(bb * HEADS + h) * HEAD_DIM + d) * SEQ + s] = __float2bfloat16(val);
                } else {
                    ((float*)dstv)[(size_t)m * N + n] = val;
                }
            }
        }
    }
}

// ---------------- RoPE pointwise: writes hi half of tgt (B,H,S,128) ----------------
__global__ __launch_bounds__(256) void rope_pt_kernel(
    const bf16* __restrict__ t2, const float* __restrict__ cosT,
    const float* __restrict__ sinT, bf16* __restrict__ tgt)
{
    int gid = blockIdx.x * blockDim.x + threadIdx.x;   // B*H*S*32 = 2^21
    int j = gid & 31;
    int s = (gid >> 5) & 2047;
    int h = (gid >> 16) & 15;
    int b = gid >> 20;
    const bf16* row = t2 + ((size_t)(b * SEQ + s) * HEADS + h) * 64;
    float rot = bf2f(((const u16*)row)[j]);
    float pas = bf2f(((const u16*)row)[j + 32]);
    float c = cosT[s * 32 + j], sn = sinT[s * 32 + j];
    bf16* o = tgt + ((size_t)(b * HEADS + h) * SEQ + s) * HEAD_DIM + 64;
    o[j] = __float2bfloat16(rot * c - pas * sn);
    o[j + 32] = __float2bfloat16(rot * sn + pas * c);
}

// ---------------- MFMA causal flash attention ----------------
// q,k: (B,H,S,128); vt: (B,H,128,S); out: (B,S,H*128) bf16
__global__ __launch_bounds__(256) void attn_mfma_kernel(
    const bf16* __restrict__ qg, const bf16* __restrict__ kg,
    const bf16* __restrict__ vtg, bf16* __restrict__ outp)
{
    const int qt = blockIdx.x, h = blockIdx.y, b = blockIdx.z;
    const int tid = threadIdx.x;
    const int w = tid >> 6, lane = tid & 63;
    const int fr = lane & 15, fq = lane >> 4;
    const int q0 = qt * 64;

    const bf16* Q  = qg  + (size_t)(b * HEADS + h) * SEQ * HEAD_DIM;
    const bf16* K  = kg  + (size_t)(b * HEADS + h) * SEQ * HEAD_DIM;
    const bf16* Vt = vtg + (size_t)(b * HEADS + h) * HEAD_DIM * SEQ;

    constexpr int LK = 136;   // shorts; 272 B row
    constexpr int LV = 72;
    constexpr int LP = 72;
    __shared__ short Ks[64 * LK];
    __shared__ short Vs[128 * LV];
    __shared__ short Ps[64 * LP];

    // Q fragments (A-operand) in registers: row = w*16+fr, k = kk*32 + fq*8
    bf16x8 qf[4];
#pragma unroll
    for (int kk = 0; kk < 4; kk++)
        qf[kk] = *(const bf16x8*)(Q + (size_t)(q0 + w * 16 + fr) * HEAD_DIM + kk * 32 + fq * 8);

    f32x4 accO[8];
#pragma unroll
    for (int ci = 0; ci < 8; ci++) accO[ci] = (f32x4){0.f, 0.f, 0.f, 0.f};
    float m[4] = {-INFINITY, -INFINITY, -INFINITY, -INFINITY};
    float l[4] = {0.f, 0.f, 0.f, 0.f};

    for (int kt = 0; kt <= qt; kt++) {
        __syncthreads();   // prev PV (Vs/Ps reads) done before restage
        // stage K tile [64][128]
#pragma unroll
        for (int p = 0; p < 4; p++) {
            int lin = tid + p * 256;
            int row = lin >> 4, ch = lin & 15;
            *(uint4*)&Ks[row * LK + ch * 8] = *(const uint4*)(K + (size_t)(kt * 64 + row) * HEAD_DIM + ch * 8);
        }
        // stage Vt tile [128][64]
#pragma unroll
        for (int p = 0; p < 4; p++) {
            int lin = tid + p * 256;
            int row = lin >> 3, ch = lin & 7;
            *(uint4*)&Vs[row * LV + ch * 8] = *(const uint4*)(Vt + (size_t)row * SEQ + kt * 64 + ch * 8);
        }
        __syncthreads();

        // QK^T: accS[ni] — C layout: row = fq*4+reg (q-row in strip), col = ni*16+fr (key)
        f32x4 accS[4];
#pragma unroll
        for (int ni = 0; ni < 4; ni++) accS[ni] = (f32x4){0.f, 0.f, 0.f, 0.f};
#pragma unroll
        for (int kk = 0; kk < 4; kk++) {
#pragma unroll
            for (int ni = 0; ni < 4; ni++) {
                bf16x8 kf = *(const bf16x8*)&Ks[(ni * 16 + fr) * LK + kk * 32 + fq * 8];
                accS[ni] = __builtin_amdgcn_mfma_f32_16x16x32_bf16(qf[kk], kf, accS[ni], 0, 0, 0);
            }
        }

        // scale + causal mask (only diagonal tile needs it)
        const bool diag = (kt == qt);
        float sv[4][4];   // [ni][reg]
#pragma unroll
        for (int ni = 0; ni < 4; ni++)
#pragma unroll
            for (int reg = 0; reg < 4; reg++) {
                float s = accS[ni][reg] * ATTN_SCALE;
                if (diag) {
                    int col = ni * 16 + fr;
                    int row = w * 16 + fq * 4 + reg;
                    if (col > row) s = -INFINITY;
                }
                sv[ni][reg] = s;
            }

        // online softmax: row reduce over 16 lanes (xor of low 4 bits keeps fq fixed)
        float mt[4];
#pragma unroll
        for (int reg = 0; reg < 4; reg++)
            mt[reg] = fmaxf(fmaxf(sv[0][reg], sv[1][reg]), fmaxf(sv[2][reg], sv[3][reg]));
#pragma unroll
        for (int mk = 1; mk < 16; mk <<= 1)
#pragma unroll
            for (int reg = 0; reg < 4; reg++)
                mt[reg] = fmaxf(mt[reg], __shfl_xor(mt[reg], mk));
        float rs[4];
#pragma unroll
        for (int reg = 0; reg < 4; reg++) {
            float mn = fmaxf(m[reg], mt[reg]);
            rs[reg] = __expf(m[reg] - mn);
            m[reg] = mn;
        }
        float sum[4] = {0.f, 0.f, 0.f, 0.f};
#pragma unroll
        for (int ni = 0; ni < 4; ni++)
#pragma unroll
            for (int reg = 0; reg < 4; reg++) {
                float p = __expf(sv[ni][reg] - m[reg]);
                sv[ni][reg] = p;
                sum[reg] += p;
            }
#pragma unroll
        for (int mk = 1; mk < 16; mk <<= 1)
#pragma unroll
            for (int reg = 0; reg < 4; reg++)
                sum[reg] += __shfl_xor(sum[reg], mk);
#pragma unroll
        for (int reg = 0; reg < 4; reg++)
            l[reg] = l[reg] * rs[reg] + sum[reg];
#pragma unroll
        for (int ci = 0; ci < 8; ci++)
#pragma unroll
            for (int reg = 0; reg < 4; reg++)
                accO[ci][reg] *= rs[reg];

        // write P (bf16) to LDS [row][key], row-major: PV A-operand
#pragma unroll
        for (int ni = 0; ni < 4; ni++)
#pragma unroll
            for (int reg = 0; reg < 4; reg++)
                Ps[(w * 16 + fq * 4 + reg) * LP + ni * 16 + fr] = f2bf_s(sv[ni][reg]);
        __syncthreads();

        // PV: accO[ci] += P[16x64] @ Vt^T  (A = Ps rows, B = Vs rows)
#pragma unroll
        for (int kk = 0; kk < 2; kk++) {
            bf16x8 pf = *(const bf16x8*)&Ps[(w * 16 + fr) * LP + kk * 32 + fq * 8];
#pragma unroll
            for (int ci = 0; ci < 8; ci++) {
                bf16x8 vf = *(const bf16x8*)&Vs[(ci * 16 + fr) * LV + kk * 32 + fq * 8];
                accO[ci] = __builtin_amdgcn_mfma_f32_16x16x32_bf16(pf, vf, accO[ci], 0, 0, 0);
            }
        }
    }

    // epilogue: out[(b*S + q0 + w*16 + fq*4+reg)*2048 + h*128 + ci*16+fr]
    float inv[4];
#pragma unroll
    for (int reg = 0; reg < 4; reg++) inv[reg] = 1.0f / l[reg];
#pragma unroll
    for (int reg = 0; reg < 4; reg++) {
        bf16* dst = outp + ((size_t)(b * SEQ) + q0 + w * 16 + fq * 4 + reg) * HIDDEN + h * HEAD_DIM + fr;
#pragma unroll
        for (int ci = 0; ci < 8; ci++)
            dst[ci * 16] = __float2bfloat16(accO[ci][reg] * inv[reg]);
    }
}

extern "C" void kernel_launch(void* const* d_in, const int* in_sizes, int n_in,
                              void* d_out, int out_size, void* d_ws, size_t ws_size,
                              hipStream_t stream)
{
    const float* x      = (const float*)d_in[0];
    // d_in[1] = attention_mask (int32 causal tril) — causality implemented directly
    const float* W_kv_d = (const float*)d_in[2];
    const float* b_kv_d = (const float*)d_in[3];
    const float* W_q_d  = (const float*)d_in[4];
    const float* b_q_d  = (const float*)d_in[5];
    const float* W_k_u  = (const float*)d_in[6];
    const float* b_k_u  = (const float*)d_in[7];
    const float* W_q_u  = (const float*)d_in[8];
    const float* b_q_u  = (const float*)d_in[9];
    const float* W_v_u  = (const float*)d_in[10];
    const float* b_v_u  = (const float*)d_in[11];
    const float* W_rk   = (const float*)d_in[12];
    const float* b_rk   = (const float*)d_in[13];
    const float* W_rq   = (const float*)d_in[14];
    const float* b_rq   = (const float*)d_in[15];
    const float* W_o    = (const float*)d_in[16];
    const float* b_o    = (const float*)d_in[17];

    // ---- workspace layout (~114 MB) ----
    float* cosT = (float*)d_ws;                       // 65536 f
    float* sinT = cosT + SEQ * 32;                    // 65536 f
    bf16* kv_d  = (bf16*)(sinT + SEQ * 32);           // 4096*512
    bf16* q_d   = kv_d + (size_t)MROWS * LATENT;      // 4096*512
    bf16* qg    = q_d + (size_t)MROWS * LATENT;       // (B,H,S,128)
    bf16* kg    = qg + (size_t)BATCH * HEADS * SEQ * HEAD_DIM;   // (B,H,S,128)
    bf16* vtg   = kg + (size_t)BATCH * HEADS * SEQ * HEAD_DIM;   // (B,H,128,S)
    bf16* attnb = vtg + (size_t)BATCH * HEADS * SEQ * HEAD_DIM;  // (B,S,2048)
    bf16* t2    = attnb;                              // alias (dies before attnb written)
    bf16* xb    = attnb + (size_t)MROWS * HIDDEN;
    bf16* wt    = xb + (size_t)MROWS * HIDDEN;
    bf16* Wt_kvd = wt;
    bf16* Wt_qd  = Wt_kvd + (size_t)LATENT * HIDDEN;
    bf16* Wt_ku  = Wt_qd + (size_t)LATENT * HIDDEN;
    bf16* Wt_qu  = Wt_ku + (size_t)1024 * LATENT;
    bf16* Wt_vu  = Wt_qu + (size_t)1024 * LATENT;
    bf16* Wt_rk  = Wt_vu + (size_t)HIDDEN * LATENT;
    bf16* Wt_rq  = Wt_rk + (size_t)1024 * HIDDEN;
    bf16* Wt_o   = Wt_rq + (size_t)1024 * LATENT;

    rope_table_kernel<<<(SEQ * 32 + 255) / 256, 256, 0, stream>>>(cosT, sinT);
    castx_kernel<<<MROWS * HIDDEN / 8 / 256, 256, 0, stream>>>(x, xb);
    tcast_kernel<<<dim3(HIDDEN / 32, LATENT / 32), 256, 0, stream>>>(W_kv_d, Wt_kvd, HIDDEN, LATENT);
    tcast_kernel<<<dim3(HIDDEN / 32, LATENT / 32), 256, 0, stream>>>(W_q_d, Wt_qd, HIDDEN, LATENT);
    tcast_kernel<<<dim3(LATENT / 32, 1024 / 32), 256, 0, stream>>>(W_k_u, Wt_ku, LATENT, 1024);
    tcast_kernel<<<dim3(LATENT / 32, 1024 / 32), 256, 0, stream>>>(W_q_u, Wt_qu, LATENT, 1024);
    tcast_kernel<<<dim3(LATENT / 32, HIDDEN / 32), 256, 0, stream>>>(W_v_u, Wt_vu, LATENT, HIDDEN);
    tcast_kernel<<<dim3(HIDDEN / 32, 1024 / 32), 256, 0, stream>>>(W_rk, Wt_rk, HIDDEN, 1024);
    tcast_kernel<<<dim3(LATENT / 32, 1024 / 32), 256, 0, stream>>>(W_rq, Wt_rq, LATENT, 1024);
    tcast_kernel<<<dim3(HIDDEN / 32, HIDDEN / 32), 256, 0, stream>>>(W_o, Wt_o, HIDDEN, HIDDEN);

    // kv_d = x @ W_kv_d + b   (M=4096, N=512, K=2048)
    mfma_gemm<0><<<dim3(LATENT / 128, MROWS / 128), 256, 0, stream>>>(xb, Wt_kvd, b_kv_d, kv_d, MROWS, LATENT, HIDDEN);
    mfma_gemm<0><<<dim3(LATENT / 128, MROWS / 128), 256, 0, stream>>>(xb, Wt_qd, b_q_d, q_d, MROWS, LATENT, HIDDEN);
    // k1 -> kg lo-half (B,H,S,128)   (N=1024, K=512)
    mfma_gemm<1><<<dim3(1024 / 128, MROWS / 128), 256, 0, stream>>>(kv_d, Wt_ku, b_k_u, kg, MROWS, 1024, LATENT);
    // q1 -> qg lo-half (B,H,S,128)
    mfma_gemm<1><<<dim3(1024 / 128, MROWS / 128), 256, 0, stream>>>(q_d, Wt_qu, b_q_u, qg, MROWS, 1024, LATENT);
    // v -> vtg (B,H,128,S) transposed (N=2048, K=512)
    mfma_gemm<2><<<dim3(HIDDEN / 128, MROWS / 128), 256, 0, stream>>>(kv_d, Wt_vu, b_v_u, vtg, MROWS, HIDDEN, LATENT);
    // k2 = x @ W_rk + b -> t2        (N=1024, K=2048)
    mfma_gemm<0><<<dim3(1024 / 128, MROWS / 128), 256, 0, stream>>>(xb, Wt_rk, b_rk, t2, MROWS, 1024, HIDDEN);
    rope_pt_kernel<<<(BATCH * HEADS * SEQ * 32) / 256, 256, 0, stream>>>(t2, cosT, sinT, kg);
    // q2 = q_d @ W_rq + b -> t2      (N=1024, K=512)
    mfma_gemm<0><<<dim3(1024 / 128, MROWS / 128), 256, 0, stream>>>(q_d, Wt_rq, b_rq, t2, MROWS, 1024, LATENT);
    rope_pt_kernel<<<(BATCH * HEADS * SEQ * 32) / 256, 256, 0, stream>>>(t2, cosT, sinT, qg);

    // attention -> attnb
    attn_mfma_kernel<<<dim3(SEQ / 64, HEADS, BATCH), 256, 0, stream>>>(qg, kg, vtg, attnb);

    // out = attnb @ W_o + b_o -> fp32 d_out   (N=2048, K=2048)
    mfma_gemm<4><<<dim3(HIDDEN / 128, MROWS / 128), 256, 0, stream>>>(attnb, Wt_o, b_o, d_out, MROWS, HIDDEN, HIDDEN);
}

// Round 8
// 384.744 us; speedup vs baseline: 7.2057x; 1.1482x over previous
//
#include <hip/hip_runtime.h>
#include <hip/hip_bf16.h>
#include <math.h>

#define HIDDEN 2048
#define HEADS 16
#define HEAD_DIM 128
#define LATENT 512
#define SEQ 2048
#define BATCH 2
#define MROWS (BATCH*SEQ)
#define ATTN_SCALE 0.08838834764831845f  // 1/sqrt(128)

typedef unsigned short u16;
typedef __hip_bfloat16 bf16;
typedef __attribute__((ext_vector_type(8))) short bf16x8;
typedef __attribute__((ext_vector_type(4))) float f32x4;

__device__ inline float bf2f(u16 u) { return __uint_as_float(((unsigned)u) << 16); }
__device__ inline short f2bf_s(float v) { bf16 t = __float2bfloat16(v); return *(short*)&t; }

#define GLOAD_LDS(gp, lp) \
    __builtin_amdgcn_global_load_lds((const __attribute__((address_space(1))) unsigned int*)(gp), \
                                     (__attribute__((address_space(3))) unsigned int*)(lp), 16, 0, 0)

// ---------------- RoPE cos/sin tables: (SEQ, 32) each, fp32 ----------------
__global__ void rope_table_kernel(float* __restrict__ cosT, float* __restrict__ sinT) {
    int gid = blockIdx.x * blockDim.x + threadIdx.x;
    if (gid >= SEQ * 32) return;
    int t = gid >> 5, j = gid & 31;
    float inv = powf(10000.0f, -(float)j * (1.0f / 32.0f));
    float ang = (float)t * inv;
    cosT[gid] = cosf(ang);
    sinT[gid] = sinf(ang);
}

// ---------------- cast x (M,K fp32) -> xb (M,K bf16) ----------------
__global__ __launch_bounds__(256) void castx_kernel(const float* __restrict__ x, bf16* __restrict__ xb) {
    size_t gid = (size_t)blockIdx.x * 256 + threadIdx.x;   // 8 elems per thread
    const float* p = x + gid * 8;
    float4 a = *(const float4*)p;
    float4 b = *(const float4*)(p + 4);
    bf16 o[8] = {__float2bfloat16(a.x), __float2bfloat16(a.y), __float2bfloat16(a.z), __float2bfloat16(a.w),
                 __float2bfloat16(b.x), __float2bfloat16(b.y), __float2bfloat16(b.z), __float2bfloat16(b.w)};
    *(uint4*)(xb + gid * 8) = *(uint4*)o;
}

// ---------------- transpose-cast W (K,N fp32) -> Wt (N,K bf16) ----------------
__global__ __launch_bounds__(256) void tcast_kernel(const float* __restrict__ W, bf16* __restrict__ Wt,
                                                    int K, int N) {
    __shared__ float T[32][33];
    int k0 = blockIdx.x * 32, n0 = blockIdx.y * 32;
    int tx = threadIdx.x & 31, ty = threadIdx.x >> 5;   // ty 0..7
#pragma unroll
    for (int p = 0; p < 4; p++) {
        int kr = p * 8 + ty;
        T[kr][tx] = W[(size_t)(k0 + kr) * N + n0 + tx];
    }
    __syncthreads();
#pragma unroll
    for (int p = 0; p < 4; p++) {
        int nr = p * 8 + ty;
        Wt[(size_t)(n0 + nr) * K + k0 + tx] = __float2bfloat16(T[tx][nr]);
    }
}

// ---------------- MFMA GEMM: dst = A(MxK,bf16) @ Wt^T(N,K,bf16) + bias(fp32) ----------------
// global_load_lds staging (m97 structure), linear LDS, double-buffered.
// MODE 0: bf16 plain dst[m*N+n]
// MODE 1: bf16 qk-scatter (B,H,S,128) lo-half (h=n>>6, d=n&63)
// MODE 2: bf16 v-transpose-scatter (B,H,128,S) (h=n>>7, d=n&127)
// MODE 4: fp32 plain dst[m*N+n]
template<int MODE>
__global__ __launch_bounds__(256) void mfma_gemm(
    const bf16* __restrict__ A, const bf16* __restrict__ Bt,
    const float* __restrict__ bias, void* __restrict__ dstv,
    int M, int N, int K)
{
    constexpr int BM = 128, BN = 128, BK = 32;
    __shared__ __align__(16) short As[2][BM * BK];
    __shared__ __align__(16) short Bs[2][BN * BK];

    const int tid = threadIdx.x;
    const int wid = tid >> 6;                   // wave 0..3
    const int lane = tid & 63;
    const int wm = (wid >> 1) * 64;
    const int wn = (wid & 1) * 64;
    const int bm = blockIdx.y * BM, bn = blockIdx.x * BN;
    const int fr = lane & 15;
    const int fk = lane >> 4;

    // staging geometry: wave w stages rows [w*32, w*32+32); per instr 16 rows,
    // lane l covers row i*16 + (l>>2), 16B chunk (l&3)*8 shorts.
    const int srowA = wid * 32 + (lane >> 2);
    const int scol = (lane & 3) * 8;

    f32x4 acc[4][4];
#pragma unroll
    for (int mi = 0; mi < 4; mi++)
#pragma unroll
        for (int ni = 0; ni < 4; ni++)
            acc[mi][ni] = (f32x4){0.f, 0.f, 0.f, 0.f};

    const int NT = K / BK;
    // prologue: stage tile 0 into buf 0
#pragma unroll
    for (int i = 0; i < 2; i++) {
        GLOAD_LDS(A + (size_t)(bm + srowA + i * 16) * K + scol, &As[0][(wid * 32 + i * 16) * BK]);
        GLOAD_LDS(Bt + (size_t)(bn + srowA + i * 16) * K + scol, &Bs[0][(wid * 32 + i * 16) * BK]);
    }

    int cur = 0;
    for (int t = 0; t < NT; t++) {
        __syncthreads();                       // drains vmcnt -> buf[cur] ready; all reads of buf[cur^1] done
        if (t + 1 < NT) {
            size_t kk = (size_t)(t + 1) * BK;
#pragma unroll
            for (int i = 0; i < 2; i++) {
                GLOAD_LDS(A + (size_t)(bm + srowA + i * 16) * K + kk + scol, &As[cur ^ 1][(wid * 32 + i * 16) * BK]);
                GLOAD_LDS(Bt + (size_t)(bn + srowA + i * 16) * K + kk + scol, &Bs[cur ^ 1][(wid * 32 + i * 16) * BK]);
            }
        }
        bf16x8 af[4], bfr[4];
#pragma unroll
        for (int mi = 0; mi < 4; mi++)
            af[mi] = *(const bf16x8*)&As[cur][(wm + mi * 16 + fr) * BK + fk * 8];
#pragma unroll
        for (int ni = 0; ni < 4; ni++)
            bfr[ni] = *(const bf16x8*)&Bs[cur][(wn + ni * 16 + fr) * BK + fk * 8];
#pragma unroll
        for (int mi = 0; mi < 4; mi++)
#pragma unroll
            for (int ni = 0; ni < 4; ni++)
                acc[mi][ni] = __builtin_amdgcn_mfma_f32_16x16x32_bf16(af[mi], bfr[ni], acc[mi][ni], 0, 0, 0);
        cur ^= 1;
    }

    // epilogue: C/D layout col=lane&15, row=(lane>>4)*4+reg
    const int cr = (lane >> 4) * 4;
    bf16* dst = (bf16*)dstv;
#pragma unroll
    for (int mi = 0; mi < 4; mi++) {
#pragma unroll
        for (int j = 0; j < 4; j++) {
            int m = bm + wm + mi * 16 + cr + j;
            int bb = m >> 11;                   // / SEQ
            int s = m & 2047;
#pragma unroll
            for (int ni = 0; ni < 4; ni++) {
                int n = bn + wn + ni * 16 + fr;
                float val = acc[mi][ni][j] + bias[n];
                if constexpr (MODE == 0) {
                    dst[(size_t)m * N + n] = __float2bfloat16(val);
                } else if constexpr (MODE == 1) {
                    int h = n >> 6, d = n & 63;
                    dst[((size_t)(bb * HEADS + h) * SEQ + s) * HEAD_DIM + d] = __float2bfloat16(val);
                } else if constexpr (MODE == 2) {
                    int h = n >> 7, d = n & 127;
                    dst[((size_t)(bb * HEADS + h) * HEAD_DIM + d) * SEQ + s] = __float2bfloat16(val);
                } else {
                    ((float*)dstv)[(size_t)m * N + n] = val;
                }
            }
        }
    }
}

// ---------------- RoPE pointwise: writes hi half of tgt (B,H,S,128) ----------------
__global__ __launch_bounds__(256) void rope_pt_kernel(
    const bf16* __restrict__ t2, const float* __restrict__ cosT,
    const float* __restrict__ sinT, bf16* __restrict__ tgt)
{
    int gid = blockIdx.x * blockDim.x + threadIdx.x;   // B*H*S*32 = 2^21
    int j = gid & 31;
    int s = (gid >> 5) & 2047;
    int h = (gid >> 16) & 15;
    int b = gid >> 20;
    const bf16* row = t2 + ((size_t)(b * SEQ + s) * HEADS + h) * 64;
    float rot = bf2f(((const u16*)row)[j]);
    float pas = bf2f(((const u16*)row)[j + 32]);
    float c = cosT[s * 32 + j], sn = sinT[s * 32 + j];
    bf16* o = tgt + ((size_t)(b * HEADS + h) * SEQ + s) * HEAD_DIM + 64;
    o[j] = __float2bfloat16(rot * c - pas * sn);
    o[j + 32] = __float2bfloat16(rot * sn + pas * c);
}

// ---------------- MFMA causal flash attention, swapped-QK softmax, paired q-tiles ----------------
// q,k: (B,H,S,128); vt: (B,H,128,S); out: (B,S,H*128) bf16
// grid: 512 blocks 1D. f -> xcd=f&7, slot=f>>3; (b,h) group g=xcd*4+(slot>>4); pid=slot&15.
// block handles q-tiles pid and 31-pid (uniform 33 KV-tiles of work).
__global__ __launch_bounds__(256) void attn_mfma_kernel(
    const bf16* __restrict__ qg, const bf16* __restrict__ kg,
    const bf16* __restrict__ vtg, bf16* __restrict__ outp)
{
    const int f = blockIdx.x;
    const int xcd = f & 7, slot = f >> 3;
    const int g = xcd * 4 + (slot >> 4);   // (b,h) group: all 16 pair-blocks of g share one XCD
    const int pid = slot & 15;
    const int b = g >> 4, h = g & 15;

    const int tid = threadIdx.x;
    const int w = tid >> 6, lane = tid & 63;
    const int fr = lane & 15, fq = lane >> 4;

    const bf16* Q  = qg  + (size_t)(b * HEADS + h) * SEQ * HEAD_DIM;
    const bf16* K  = kg  + (size_t)(b * HEADS + h) * SEQ * HEAD_DIM;
    const bf16* Vt = vtg + (size_t)(b * HEADS + h) * HEAD_DIM * SEQ;

    constexpr int LK = 136;
    constexpr int LV = 72;
    constexpr int LP = 72;
    __shared__ __align__(16) short Ks[64 * LK];
    __shared__ __align__(16) short Vs[128 * LV];
    __shared__ __align__(16) short Ps[64 * LP];

#pragma unroll 1
    for (int seg = 0; seg < 2; seg++) {
        const int qt = seg ? (31 - pid) : pid;
        const int q0 = qt * 64;
        const int qrow = q0 + w * 16 + fr;     // this lane's q-row (swapped layout)

        // Q fragments (B-operand now): lane supplies Q[q=w*16+fr][fq*8..]
        bf16x8 qf[4];
#pragma unroll
        for (int kk = 0; kk < 4; kk++)
            qf[kk] = *(const bf16x8*)(Q + (size_t)(q0 + w * 16 + fr) * HEAD_DIM + kk * 32 + fq * 8);

        f32x4 accO[8];
#pragma unroll
        for (int ci = 0; ci < 8; ci++) accO[ci] = (f32x4){0.f, 0.f, 0.f, 0.f};
        float m_run = -INFINITY, l_run = 0.f;

        for (int kt = 0; kt <= qt; kt++) {
            __syncthreads();   // prev PV reads done before restage
            // stage K tile [64][128]
#pragma unroll
            for (int p = 0; p < 4; p++) {
                int lin = tid + p * 256;
                int row = lin >> 4, ch = lin & 15;
                *(uint4*)&Ks[row * LK + ch * 8] = *(const uint4*)(K + (size_t)(kt * 64 + row) * HEAD_DIM + ch * 8);
            }
            // stage Vt tile [128][64]
#pragma unroll
            for (int p = 0; p < 4; p++) {
                int lin = tid + p * 256;
                int row = lin >> 3, ch = lin & 7;
                *(uint4*)&Vs[row * LV + ch * 8] = *(const uint4*)(Vt + (size_t)row * SEQ + kt * 64 + ch * 8);
            }
            __syncthreads();

            // QK^T swapped: A=K (rows=key), B=Q (rows=q).
            // C: col=fr=q, row=fq*4+reg=key_sub; key = kt*64 + ni*16 + fq*4 + reg
            f32x4 accS[4];
#pragma unroll
            for (int ni = 0; ni < 4; ni++) accS[ni] = (f32x4){0.f, 0.f, 0.f, 0.f};
#pragma unroll
            for (int kk = 0; kk < 4; kk++) {
#pragma unroll
                for (int ni = 0; ni < 4; ni++) {
                    bf16x8 kf = *(const bf16x8*)&Ks[(ni * 16 + fr) * LK + kk * 32 + fq * 8];
                    accS[ni] = __builtin_amdgcn_mfma_f32_16x16x32_bf16(kf, qf[kk], accS[ni], 0, 0, 0);
                }
            }

            // lane-local softmax over this lane's 16 keys of its q-row
            const bool diag = (kt == qt);
            float pv[16];
            float mloc = -INFINITY;
#pragma unroll
            for (int ni = 0; ni < 4; ni++)
#pragma unroll
                for (int reg = 0; reg < 4; reg++) {
                    float s = accS[ni][reg] * ATTN_SCALE;
                    int key = kt * 64 + ni * 16 + fq * 4 + reg;
                    if (diag && key > qrow) s = -INFINITY;
                    pv[ni * 4 + reg] = s;
                    mloc = fmaxf(mloc, s);
                }
            // reduce over the 4 lanes sharing this q-row (fq group: xor bits 4,5)
            mloc = fmaxf(mloc, __shfl_xor(mloc, 16));
            mloc = fmaxf(mloc, __shfl_xor(mloc, 32));
            float mn = fmaxf(m_run, mloc);
            float rs = __expf(m_run - mn);
            m_run = mn;
            float sum = 0.f;
#pragma unroll
            for (int i = 0; i < 16; i++) {
                float p = __expf(pv[i] - mn);
                pv[i] = p;
                sum += p;
            }
            sum += __shfl_xor(sum, 16);
            sum += __shfl_xor(sum, 32);
            l_run = l_run * rs + sum;

            // broadcast rs to accO's row indexing (row = fq*4+reg)
            float rsb[4];
#pragma unroll
            for (int reg = 0; reg < 4; reg++) rsb[reg] = __shfl(rs, fq * 4 + reg);
#pragma unroll
            for (int ci = 0; ci < 8; ci++)
#pragma unroll
                for (int reg = 0; reg < 4; reg++)
                    accO[ci][reg] *= rsb[reg];

            // P write: lane owns 4 consecutive keys per ni -> packed 8B ds_write
#pragma unroll
            for (int ni = 0; ni < 4; ni++) {
                unsigned lo = (unsigned)(u16)f2bf_s(pv[ni * 4 + 0]) | ((unsigned)(u16)f2bf_s(pv[ni * 4 + 1]) << 16);
                unsigned hi = (unsigned)(u16)f2bf_s(pv[ni * 4 + 2]) | ((unsigned)(u16)f2bf_s(pv[ni * 4 + 3]) << 16);
                uint2 u; u.x = lo; u.y = hi;
                *(uint2*)&Ps[(w * 16 + fr) * LP + ni * 16 + fq * 4] = u;
            }
            __syncthreads();

            // PV: A = Ps (rows=q), B = Vs (rows=d); C: col=fr=d_sub, row=fq*4+reg=q_sub
#pragma unroll
            for (int kk = 0; kk < 2; kk++) {
                bf16x8 pf = *(const bf16x8*)&Ps[(w * 16 + fr) * LP + kk * 32 + fq * 8];
#pragma unroll
                for (int ci = 0; ci < 8; ci++) {
                    bf16x8 vf = *(const bf16x8*)&Vs[(ci * 16 + fr) * LV + kk * 32 + fq * 8];
                    accO[ci] = __builtin_amdgcn_mfma_f32_16x16x32_bf16(pf, vf, accO[ci], 0, 0, 0);
                }
            }
        }

        // epilogue: accO row q_sub = fq*4+reg; need 1/l of that q-row (held at lane fr=q_sub)
        float linv = 1.0f / l_run;
#pragma unroll
        for (int reg = 0; reg < 4; reg++) {
            float invb = __shfl(linv, fq * 4 + reg);
            bf16* dst = outp + ((size_t)(b * SEQ) + q0 + w * 16 + fq * 4 + reg) * HIDDEN + h * HEAD_DIM + fr;
#pragma unroll
            for (int ci = 0; ci < 8; ci++)
                dst[ci * 16] = __float2bfloat16(accO[ci][reg] * invb);
        }
    }
}

extern "C" void kernel_launch(void* const* d_in, const int* in_sizes, int n_in,
                              void* d_out, int out_size, void* d_ws, size_t ws_size,
                              hipStream_t stream)
{
    const float* x      = (const float*)d_in[0];
    // d_in[1] = attention_mask (int32 causal tril) — causality implemented directly
    const float* W_kv_d = (const float*)d_in[2];
    const float* b_kv_d = (const float*)d_in[3];
    const float* W_q_d  = (const float*)d_in[4];
    const float* b_q_d  = (const float*)d_in[5];
    const float* W_k_u  = (const float*)d_in[6];
    const float* b_k_u  = (const float*)d_in[7];
    const float* W_q_u  = (const float*)d_in[8];
    const float* b_q_u  = (const float*)d_in[9];
    const float* W_v_u  = (const float*)d_in[10];
    const float* b_v_u  = (const float*)d_in[11];
    const float* W_rk   = (const float*)d_in[12];
    const float* b_rk   = (const float*)d_in[13];
    const float* W_rq   = (const float*)d_in[14];
    const float* b_rq   = (const float*)d_in[15];
    const float* W_o    = (const float*)d_in[16];
    const float* b_o    = (const float*)d_in[17];

    // ---- workspace layout (~114 MB) ----
    float* cosT = (float*)d_ws;                       // 65536 f
    float* sinT = cosT + SEQ * 32;                    // 65536 f
    bf16* kv_d  = (bf16*)(sinT + SEQ * 32);           // 4096*512
    bf16* q_d   = kv_d + (size_t)MROWS * LATENT;      // 4096*512
    bf16* qg    = q_d + (size_t)MROWS * LATENT;       // (B,H,S,128)
    bf16* kg    = qg + (size_t)BATCH * HEADS * SEQ * HEAD_DIM;   // (B,H,S,128)
    bf16* vtg   = kg + (size_t)BATCH * HEADS * SEQ * HEAD_DIM;   // (B,H,128,S)
    bf16* attnb = vtg + (size_t)BATCH * HEADS * SEQ * HEAD_DIM;  // (B,S,2048)
    bf16* t2    = attnb;                              // alias (dies before attnb written)
    bf16* xb    = attnb + (size_t)MROWS * HIDDEN;
    bf16* wt    = xb + (size_t)MROWS * HIDDEN;
    bf16* Wt_kvd = wt;
    bf16* Wt_qd  = Wt_kvd + (size_t)LATENT * HIDDEN;
    bf16* Wt_ku  = Wt_qd + (size_t)LATENT * HIDDEN;
    bf16* Wt_qu  = Wt_ku + (size_t)1024 * LATENT;
    bf16* Wt_vu  = Wt_qu + (size_t)1024 * LATENT;
    bf16* Wt_rk  = Wt_vu + (size_t)HIDDEN * LATENT;
    bf16* Wt_rq  = Wt_rk + (size_t)1024 * HIDDEN;
    bf16* Wt_o   = Wt_rq + (size_t)1024 * LATENT;

    rope_table_kernel<<<(SEQ * 32 + 255) / 256, 256, 0, stream>>>(cosT, sinT);
    castx_kernel<<<MROWS * HIDDEN / 8 / 256, 256, 0, stream>>>(x, xb);
    tcast_kernel<<<dim3(HIDDEN / 32, LATENT / 32), 256, 0, stream>>>(W_kv_d, Wt_kvd, HIDDEN, LATENT);
    tcast_kernel<<<dim3(HIDDEN / 32, LATENT / 32), 256, 0, stream>>>(W_q_d, Wt_qd, HIDDEN, LATENT);
    tcast_kernel<<<dim3(LATENT / 32, 1024 / 32), 256, 0, stream>>>(W_k_u, Wt_ku, LATENT, 1024);
    tcast_kernel<<<dim3(LATENT / 32, 1024 / 32), 256, 0, stream>>>(W_q_u, Wt_qu, LATENT, 1024);
    tcast_kernel<<<dim3(LATENT / 32, HIDDEN / 32), 256, 0, stream>>>(W_v_u, Wt_vu, LATENT, HIDDEN);
    tcast_kernel<<<dim3(HIDDEN / 32, 1024 / 32), 256, 0, stream>>>(W_rk, Wt_rk, HIDDEN, 1024);
    tcast_kernel<<<dim3(LATENT / 32, 1024 / 32), 256, 0, stream>>>(W_rq, Wt_rq, LATENT, 1024);
    tcast_kernel<<<dim3(HIDDEN / 32, HIDDEN / 32), 256, 0, stream>>>(W_o, Wt_o, HIDDEN, HIDDEN);

    // kv_d = x @ W_kv_d + b   (M=4096, N=512, K=2048)
    mfma_gemm<0><<<dim3(LATENT / 128, MROWS / 128), 256, 0, stream>>>(xb, Wt_kvd, b_kv_d, kv_d, MROWS, LATENT, HIDDEN);
    mfma_gemm<0><<<dim3(LATENT / 128, MROWS / 128), 256, 0, stream>>>(xb, Wt_qd, b_q_d, q_d, MROWS, LATENT, HIDDEN);
    // k1 -> kg lo-half (B,H,S,128)   (N=1024, K=512)
    mfma_gemm<1><<<dim3(1024 / 128, MROWS / 128), 256, 0, stream>>>(kv_d, Wt_ku, b_k_u, kg, MROWS, 1024, LATENT);
    // q1 -> qg lo-half (B,H,S,128)
    mfma_gemm<1><<<dim3(1024 / 128, MROWS / 128), 256, 0, stream>>>(q_d, Wt_qu, b_q_u, qg, MROWS, 1024, LATENT);
    // v -> vtg (B,H,128,S) transposed (N=2048, K=512)
    mfma_gemm<2><<<dim3(HIDDEN / 128, MROWS / 128), 256, 0, stream>>>(kv_d, Wt_vu, b_v_u, vtg, MROWS, HIDDEN, LATENT);
    // k2 = x @ W_rk + b -> t2        (N=1024, K=2048)
    mfma_gemm<0><<<dim3(1024 / 128, MROWS / 128), 256, 0, stream>>>(xb, Wt_rk, b_rk, t2, MROWS, 1024, HIDDEN);
    rope_pt_kernel<<<(BATCH * HEADS * SEQ * 32) / 256, 256, 0, stream>>>(t2, cosT, sinT, kg);
    // q2 = q_d @ W_rq + b -> t2      (N=1024, K=512)
    mfma_gemm<0><<<dim3(1024 / 128, MROWS / 128), 256, 0, stream>>>(q_d, Wt_rq, b_rq, t2, MROWS, 1024, LATENT);
    rope_pt_kernel<<<(BATCH * HEADS * SEQ * 32) / 256, 256, 0, stream>>>(t2, cosT, sinT, qg);

    // attention -> attnb (512 paired, XCD-grouped blocks)
    attn_mfma_kernel<<<512, 256, 0, stream>>>(qg, kg, vtg, attnb);

    // out = attnb @ W_o + b_o -> fp32 d_out   (N=2048, K=2048)
    mfma_gemm<4><<<dim3(HIDDEN / 128, MROWS / 128), 256, 0, stream>>>(attnb, Wt_o, b_o, d_out, MROWS, HIDDEN, HIDDEN);
}

// Round 9
// 351.887 us; speedup vs baseline: 7.8785x; 1.0934x over previous
//
#include <hip/hip_runtime.h>
#include <hip/hip_bf16.h>
#include <math.h>

#define HIDDEN 2048
#define HEADS 16
#define HEAD_DIM 128
#define LATENT 512
#define SEQ 2048
#define BATCH 2
#define MROWS (BATCH*SEQ)
#define ATTN_SCALE 0.08838834764831845f  // 1/sqrt(128)

typedef unsigned short u16;
typedef __hip_bfloat16 bf16;
typedef __attribute__((ext_vector_type(8))) short bf16x8;
typedef __attribute__((ext_vector_type(4))) float f32x4;

__device__ inline float bf2f(u16 u) { return __uint_as_float(((unsigned)u) << 16); }
__device__ inline short f2bf_s(float v) { bf16 t = __float2bfloat16(v); return *(short*)&t; }

#define GLOAD_LDS(gp, lp) \
    __builtin_amdgcn_global_load_lds((const __attribute__((address_space(1))) unsigned int*)(gp), \
                                     (__attribute__((address_space(3))) unsigned int*)(lp), 16, 0, 0)

// ---------------- RoPE cos/sin tables: (SEQ, 32) each, fp32 ----------------
__global__ void rope_table_kernel(float* __restrict__ cosT, float* __restrict__ sinT) {
    int gid = blockIdx.x * blockDim.x + threadIdx.x;
    if (gid >= SEQ * 32) return;
    int t = gid >> 5, j = gid & 31;
    float inv = powf(10000.0f, -(float)j * (1.0f / 32.0f));
    float ang = (float)t * inv;
    cosT[gid] = cosf(ang);
    sinT[gid] = sinf(ang);
}

// ---------------- cast x (M,K fp32) -> xb (M,K bf16) ----------------
__global__ __launch_bounds__(256) void castx_kernel(const float* __restrict__ x, bf16* __restrict__ xb) {
    size_t gid = (size_t)blockIdx.x * 256 + threadIdx.x;   // 8 elems per thread
    const float* p = x + gid * 8;
    float4 a = *(const float4*)p;
    float4 b = *(const float4*)(p + 4);
    bf16 o[8] = {__float2bfloat16(a.x), __float2bfloat16(a.y), __float2bfloat16(a.z), __float2bfloat16(a.w),
                 __float2bfloat16(b.x), __float2bfloat16(b.y), __float2bfloat16(b.z), __float2bfloat16(b.w)};
    *(uint4*)(xb + gid * 8) = *(uint4*)o;
}

// ---------------- transpose-cast W (K,N fp32) -> Wt (N,K bf16) ----------------
__global__ __launch_bounds__(256) void tcast_kernel(const float* __restrict__ W, bf16* __restrict__ Wt,
                                                    int K, int N) {
    __shared__ float T[32][33];
    int k0 = blockIdx.x * 32, n0 = blockIdx.y * 32;
    int tx = threadIdx.x & 31, ty = threadIdx.x >> 5;   // ty 0..7
#pragma unroll
    for (int p = 0; p < 4; p++) {
        int kr = p * 8 + ty;
        T[kr][tx] = W[(size_t)(k0 + kr) * N + n0 + tx];
    }
    __syncthreads();
#pragma unroll
    for (int p = 0; p < 4; p++) {
        int nr = p * 8 + ty;
        Wt[(size_t)(n0 + nr) * K + k0 + tx] = __float2bfloat16(T[tx][nr]);
    }
}

// ---------------- fused MFMA GEMM ----------------
// A(MxK bf16) @ Wt^T(N,K bf16) + bias, epilogue per FUSE (segment branch on bn, uniform per block):
// FUSE 1: [0,512) plain->d0(kv_d,b0); [512,1024) plain->d1(q_d,b1); [1024,2048) rope-scatter->d2(kg hi,b2)
// FUSE 2: [0,1024) k1-scatter lo->d0(kg,b0); [1024,3072) v-transpose->d1(vtg,b1)
// FUSE 3: [0,1024) q1-scatter lo->d0(qg,b0); [1024,2048) rope-scatter->d1(qg hi,b1)
// FUSE 4: fp32 plain->d0(b0)
template<int FUSE>
__global__ __launch_bounds__(256) void mfma_gemm(
    const bf16* __restrict__ A, const bf16* __restrict__ Bt,
    const float* __restrict__ bias0, const float* __restrict__ bias1, const float* __restrict__ bias2,
    void* __restrict__ d0, void* __restrict__ d1, void* __restrict__ d2,
    const float* __restrict__ cosT, const float* __restrict__ sinT,
    int M, int N, int K)
{
    constexpr int BM = 128, BN = 128, BK = 32;
    __shared__ __align__(16) short As[2][BM * BK];
    __shared__ __align__(16) short Bs[2][BN * BK];

    const int tid = threadIdx.x;
    const int wid = tid >> 6;
    const int lane = tid & 63;
    const int wm = (wid >> 1) * 64;
    const int wn = (wid & 1) * 64;
    const int bm = blockIdx.y * BM, bn = blockIdx.x * BN;
    const int fr = lane & 15;
    const int fk = lane >> 4;

    const int srowA = wid * 32 + (lane >> 2);
    const int scol = (lane & 3) * 8;

    f32x4 acc[4][4];
#pragma unroll
    for (int mi = 0; mi < 4; mi++)
#pragma unroll
        for (int ni = 0; ni < 4; ni++)
            acc[mi][ni] = (f32x4){0.f, 0.f, 0.f, 0.f};

    const int NT = K / BK;
#pragma unroll
    for (int i = 0; i < 2; i++) {
        GLOAD_LDS(A + (size_t)(bm + srowA + i * 16) * K + scol, &As[0][(wid * 32 + i * 16) * BK]);
        GLOAD_LDS(Bt + (size_t)(bn + srowA + i * 16) * K + scol, &Bs[0][(wid * 32 + i * 16) * BK]);
    }

    int cur = 0;
    for (int t = 0; t < NT; t++) {
        __syncthreads();
        if (t + 1 < NT) {
            size_t kk = (size_t)(t + 1) * BK;
#pragma unroll
            for (int i = 0; i < 2; i++) {
                GLOAD_LDS(A + (size_t)(bm + srowA + i * 16) * K + kk + scol, &As[cur ^ 1][(wid * 32 + i * 16) * BK]);
                GLOAD_LDS(Bt + (size_t)(bn + srowA + i * 16) * K + kk + scol, &Bs[cur ^ 1][(wid * 32 + i * 16) * BK]);
            }
        }
        bf16x8 af[4], bfr[4];
#pragma unroll
        for (int mi = 0; mi < 4; mi++)
            af[mi] = *(const bf16x8*)&As[cur][(wm + mi * 16 + fr) * BK + fk * 8];
#pragma unroll
        for (int ni = 0; ni < 4; ni++)
            bfr[ni] = *(const bf16x8*)&Bs[cur][(wn + ni * 16 + fr) * BK + fk * 8];
#pragma unroll
        for (int mi = 0; mi < 4; mi++)
#pragma unroll
            for (int ni = 0; ni < 4; ni++)
                acc[mi][ni] = __builtin_amdgcn_mfma_f32_16x16x32_bf16(af[mi], bfr[ni], acc[mi][ni], 0, 0, 0);
        cur ^= 1;
    }

    // epilogue: C/D layout col=lane&15, row=(lane>>4)*4+reg
    const int cr = (lane >> 4) * 4;
#pragma unroll
    for (int mi = 0; mi < 4; mi++) {
#pragma unroll
        for (int j = 0; j < 4; j++) {
            int m = bm + wm + mi * 16 + cr + j;
            int bb = m >> 11;          // / SEQ
            int s = m & 2047;

            if constexpr (FUSE == 4) {
#pragma unroll
                for (int ni = 0; ni < 4; ni++) {
                    int n = bn + wn + ni * 16 + fr;
                    ((float*)d0)[(size_t)m * N + n] = acc[mi][ni][j] + bias0[n];
                }
            } else if constexpr (FUSE == 1) {
                if (bn < 512) {
#pragma unroll
                    for (int ni = 0; ni < 4; ni++) {
                        int n = bn + wn + ni * 16 + fr;
                        ((bf16*)d0)[(size_t)m * 512 + n] = __float2bfloat16(acc[mi][ni][j] + bias0[n]);
                    }
                } else if (bn < 1024) {
#pragma unroll
                    for (int ni = 0; ni < 4; ni++) {
                        int n = bn + wn + ni * 16 + fr - 512;
                        ((bf16*)d1)[(size_t)m * 512 + n] = __float2bfloat16(acc[mi][ni][j] + bias1[n]);
                    }
                } else {
                    // rope scatter: nl = h*64 + dd (dd<32 for ni 0,1); pas at ni+2
#pragma unroll
                    for (int ni = 0; ni < 2; ni++) {
                        int nl = bn + wn + ni * 16 + fr - 1024;
                        int hh = nl >> 6, dd = nl & 63;
                        float rot = acc[mi][ni][j] + bias2[nl];
                        float pas = acc[mi][ni + 2][j] + bias2[nl + 32];
                        float c = cosT[s * 32 + dd], sn = sinT[s * 32 + dd];
                        bf16* o = (bf16*)d2 + ((size_t)(bb * HEADS + hh) * SEQ + s) * HEAD_DIM + 64 + dd;
                        o[0]  = __float2bfloat16(rot * c - pas * sn);
                        o[32] = __float2bfloat16(rot * sn + pas * c);
                    }
                }
            } else if constexpr (FUSE == 2) {
                if (bn < 1024) {
#pragma unroll
                    for (int ni = 0; ni < 4; ni++) {
                        int nl = bn + wn + ni * 16 + fr;
                        int hh = nl >> 6, dd = nl & 63;
                        ((bf16*)d0)[((size_t)(bb * HEADS + hh) * SEQ + s) * HEAD_DIM + dd] =
                            __float2bfloat16(acc[mi][ni][j] + bias0[nl]);
                    }
                } else {
#pragma unroll
                    for (int ni = 0; ni < 4; ni++) {
                        int nl = bn + wn + ni * 16 + fr - 1024;
                        int hh = nl >> 7, dd = nl & 127;
                        ((bf16*)d1)[((size_t)(bb * HEADS + hh) * HEAD_DIM + dd) * SEQ + s] =
                            __float2bfloat16(acc[mi][ni][j] + bias1[nl]);
                    }
                }
            } else {   // FUSE == 3
                if (bn < 1024) {
#pragma unroll
                    for (int ni = 0; ni < 4; ni++) {
                        int nl = bn + wn + ni * 16 + fr;
                        int hh = nl >> 6, dd = nl & 63;
                        ((bf16*)d0)[((size_t)(bb * HEADS + hh) * SEQ + s) * HEAD_DIM + dd] =
                            __float2bfloat16(acc[mi][ni][j] + bias0[nl]);
                    }
                } else {
#pragma unroll
                    for (int ni = 0; ni < 2; ni++) {
                        int nl = bn + wn + ni * 16 + fr - 1024;
                        int hh = nl >> 6, dd = nl & 63;
                        float rot = acc[mi][ni][j] + bias1[nl];
                        float pas = acc[mi][ni + 2][j] + bias1[nl + 32];
                        float c = cosT[s * 32 + dd], sn = sinT[s * 32 + dd];
                        bf16* o = (bf16*)d1 + ((size_t)(bb * HEADS + hh) * SEQ + s) * HEAD_DIM + 64 + dd;
                        o[0]  = __float2bfloat16(rot * c - pas * sn);
                        o[32] = __float2bfloat16(rot * sn + pas * c);
                    }
                }
            }
        }
    }
}

// ---------------- MFMA causal flash attention; XOR-swizzled LDS; 1 q-tile/block ----------------
// q,k: (B,H,S,128); vt: (B,H,128,S); out: (B,S,H*128) bf16
// 1024 blocks: xcd=f&7, r=f>>3; g=xcd*4+(r>>5) pins each (b,h) to one XCD; qt=r&31.
__global__ __launch_bounds__(256) void attn_mfma_kernel(
    const bf16* __restrict__ qg, const bf16* __restrict__ kg,
    const bf16* __restrict__ vtg, bf16* __restrict__ outp)
{
    const int f = blockIdx.x;
    const int xcd = f & 7, r = f >> 3;
    const int g = xcd * 4 + (r >> 5);
    const int qt = r & 31;
    const int b = g >> 4, h = g & 15;

    const int tid = threadIdx.x;
    const int w = tid >> 6, lane = tid & 63;
    const int fr = lane & 15, fq = lane >> 4;
    const int r7 = fr & 7;
    const int q0 = qt * 64;
    const int qrow = q0 + w * 16 + fr;

    const bf16* Q  = qg  + (size_t)(b * HEADS + h) * SEQ * HEAD_DIM;
    const bf16* K  = kg  + (size_t)(b * HEADS + h) * SEQ * HEAD_DIM;
    const bf16* Vt = vtg + (size_t)(b * HEADS + h) * HEAD_DIM * SEQ;

    // power-of-2 rows + XOR swizzle at 16B-chunk granularity: chunk ^= (row&7)
    __shared__ __align__(16) short Ks[64 * 128];   // [key][d]
    __shared__ __align__(16) short Vs[128 * 64];   // [d][key]
    __shared__ __align__(16) short Ps[64 * 64];    // [q][key]

    bf16x8 qf[4];
#pragma unroll
    for (int kk = 0; kk < 4; kk++)
        qf[kk] = *(const bf16x8*)(Q + (size_t)(q0 + w * 16 + fr) * HEAD_DIM + kk * 32 + fq * 8);

    f32x4 accO[8];
#pragma unroll
    for (int ci = 0; ci < 8; ci++) accO[ci] = (f32x4){0.f, 0.f, 0.f, 0.f};
    float m_run = -INFINITY, l_run = 0.f;

    for (int kt = 0; kt <= qt; kt++) {
        __syncthreads();
        // stage K tile [64 keys][128 d], swizzled
#pragma unroll
        for (int p = 0; p < 4; p++) {
            int lin = tid + p * 256;
            int row = lin >> 4, ch = lin & 15;
            *(uint4*)&Ks[row * 128 + ((ch ^ (row & 7)) * 8)] =
                *(const uint4*)(K + (size_t)(kt * 64 + row) * HEAD_DIM + ch * 8);
        }
        // stage Vt tile [128 d][64 keys], swizzled
#pragma unroll
        for (int p = 0; p < 4; p++) {
            int lin = tid + p * 256;
            int row = lin >> 3, ch = lin & 7;
            *(uint4*)&Vs[row * 64 + ((ch ^ (row & 7)) * 8)] =
                *(const uint4*)(Vt + (size_t)row * SEQ + kt * 64 + ch * 8);
        }
        __syncthreads();

        // QK^T swapped: A=K(rows=key), B=Q(rows=q). C: col=fr=q, row=fq*4+reg=key_sub
        f32x4 accS[4];
#pragma unroll
        for (int ni = 0; ni < 4; ni++) accS[ni] = (f32x4){0.f, 0.f, 0.f, 0.f};
#pragma unroll
        for (int kk = 0; kk < 4; kk++) {
#pragma unroll
            for (int ni = 0; ni < 4; ni++) {
                bf16x8 kf = *(const bf16x8*)&Ks[(ni * 16 + fr) * 128 + (((kk * 4 + fq) ^ r7) * 8)];
                accS[ni] = __builtin_amdgcn_mfma_f32_16x16x32_bf16(kf, qf[kk], accS[ni], 0, 0, 0);
            }
        }

        // lane-local softmax over this lane's 16 keys of its q-row
        const bool diag = (kt == qt);
        float pv[16];
        float mloc = -INFINITY;
#pragma unroll
        for (int ni = 0; ni < 4; ni++)
#pragma unroll
            for (int reg = 0; reg < 4; reg++) {
                float sc = accS[ni][reg] * ATTN_SCALE;
                int key = kt * 64 + ni * 16 + fq * 4 + reg;
                if (diag && key > qrow) sc = -INFINITY;
                pv[ni * 4 + reg] = sc;
                mloc = fmaxf(mloc, sc);
            }
        mloc = fmaxf(mloc, __shfl_xor(mloc, 16));
        mloc = fmaxf(mloc, __shfl_xor(mloc, 32));
        float mn = fmaxf(m_run, mloc);
        float rs = __expf(m_run - mn);
        m_run = mn;
        float sum = 0.f;
#pragma unroll
        for (int i = 0; i < 16; i++) {
            float p = __expf(pv[i] - mn);
            pv[i] = p;
            sum += p;
        }
        sum += __shfl_xor(sum, 16);
        sum += __shfl_xor(sum, 32);
        l_run = l_run * rs + sum;

        float rsb[4];
#pragma unroll
        for (int reg = 0; reg < 4; reg++) rsb[reg] = __shfl(rs, fq * 4 + reg);
#pragma unroll
        for (int ci = 0; ci < 8; ci++)
#pragma unroll
            for (int reg = 0; reg < 4; reg++)
                accO[ci][reg] *= rsb[reg];

        // P write: row=w*16+fr; logical 8B chunk (4ni+fq) -> swizzled 16B chunk (2ni+(fq>>1))^r7
#pragma unroll
        for (int ni = 0; ni < 4; ni++) {
            unsigned lo = (unsigned)(u16)f2bf_s(pv[ni * 4 + 0]) | ((unsigned)(u16)f2bf_s(pv[ni * 4 + 1]) << 16);
            unsigned hi = (unsigned)(u16)f2bf_s(pv[ni * 4 + 2]) | ((unsigned)(u16)f2bf_s(pv[ni * 4 + 3]) << 16);
            uint2 u; u.x = lo; u.y = hi;
            *(uint2*)&Ps[(w * 16 + fr) * 64 + (((2 * ni + (fq >> 1)) ^ r7) * 8) + (fq & 1) * 4] = u;
        }
        __syncthreads();

        // PV: A=Ps(rows=q), B=Vs(rows=d). C: col=fr=d_sub? no: col=fr=... row=fq*4+reg=q_sub
#pragma unroll
        for (int kk = 0; kk < 2; kk++) {
            bf16x8 pf = *(const bf16x8*)&Ps[(w * 16 + fr) * 64 + (((kk * 4 + fq) ^ r7) * 8)];
#pragma unroll
            for (int ci = 0; ci < 8; ci++) {
                bf16x8 vf = *(const bf16x8*)&Vs[(ci * 16 + fr) * 64 + (((kk * 4 + fq) ^ r7) * 8)];
                accO[ci] = __builtin_amdgcn_mfma_f32_16x16x32_bf16(pf, vf, accO[ci], 0, 0, 0);
            }
        }
    }

    // epilogue
    float linv = 1.0f / l_run;
#pragma unroll
    for (int reg = 0; reg < 4; reg++) {
        float invb = __shfl(linv, fq * 4 + reg);
        bf16* dst = outp + ((size_t)(b * SEQ) + q0 + w * 16 + fq * 4 + reg) * HIDDEN + h * HEAD_DIM + fr;
#pragma unroll
        for (int ci = 0; ci < 8; ci++)
            dst[ci * 16] = __float2bfloat16(accO[ci][reg] * invb);
    }
}

extern "C" void kernel_launch(void* const* d_in, const int* in_sizes, int n_in,
                              void* d_out, int out_size, void* d_ws, size_t ws_size,
                              hipStream_t stream)
{
    const float* x      = (const float*)d_in[0];
    // d_in[1] = attention_mask (int32 causal tril) — causality implemented directly
    const float* W_kv_d = (const float*)d_in[2];
    const float* b_kv_d = (const float*)d_in[3];
    const float* W_q_d  = (const float*)d_in[4];
    const float* b_q_d  = (const float*)d_in[5];
    const float* W_k_u  = (const float*)d_in[6];
    const float* b_k_u  = (const float*)d_in[7];
    const float* W_q_u  = (const float*)d_in[8];
    const float* b_q_u  = (const float*)d_in[9];
    const float* W_v_u  = (const float*)d_in[10];
    const float* b_v_u  = (const float*)d_in[11];
    const float* W_rk   = (const float*)d_in[12];
    const float* b_rk   = (const float*)d_in[13];
    const float* W_rq   = (const float*)d_in[14];
    const float* b_rq   = (const float*)d_in[15];
    const float* W_o    = (const float*)d_in[16];
    const float* b_o    = (const float*)d_in[17];

    // ---- workspace layout (~112 MB) ----
    float* cosT = (float*)d_ws;                       // 65536 f
    float* sinT = cosT + SEQ * 32;                    // 65536 f
    bf16* kv_d  = (bf16*)(sinT + SEQ * 32);           // 4096*512
    bf16* q_d   = kv_d + (size_t)MROWS * LATENT;      // 4096*512
    bf16* qg    = q_d + (size_t)MROWS * LATENT;       // (B,H,S,128)
    bf16* kg    = qg + (size_t)BATCH * HEADS * SEQ * HEAD_DIM;   // (B,H,S,128)
    bf16* vtg   = kg + (size_t)BATCH * HEADS * SEQ * HEAD_DIM;   // (B,H,128,S)
    bf16* attnb = vtg + (size_t)BATCH * HEADS * SEQ * HEAD_DIM;  // (B,S,2048)
    bf16* xb    = attnb + (size_t)MROWS * HIDDEN;
    bf16* Wt_g1 = xb + (size_t)MROWS * HIDDEN;        // (2048 rows, K=2048): kvd|qd|rk
    bf16* Wt_g2 = Wt_g1 + (size_t)2048 * HIDDEN;      // (3072 rows, K=512): ku|vu
    bf16* Wt_g3 = Wt_g2 + (size_t)3072 * LATENT;      // (2048 rows, K=512): qu|rq
    bf16* Wt_o  = Wt_g3 + (size_t)2048 * LATENT;      // (2048 rows, K=2048)

    rope_table_kernel<<<(SEQ * 32 + 255) / 256, 256, 0, stream>>>(cosT, sinT);
    castx_kernel<<<MROWS * HIDDEN / 8 / 256, 256, 0, stream>>>(x, xb);
    // G1 B: rows 0-511 kvd, 512-1023 qd, 1024-2047 rk (all K=2048)
    tcast_kernel<<<dim3(HIDDEN / 32, LATENT / 32), 256, 0, stream>>>(W_kv_d, Wt_g1, HIDDEN, LATENT);
    tcast_kernel<<<dim3(HIDDEN / 32, LATENT / 32), 256, 0, stream>>>(W_q_d, Wt_g1 + (size_t)512 * HIDDEN, HIDDEN, LATENT);
    tcast_kernel<<<dim3(HIDDEN / 32, 1024 / 32), 256, 0, stream>>>(W_rk, Wt_g1 + (size_t)1024 * HIDDEN, HIDDEN, 1024);
    // G2 B: rows 0-1023 ku, 1024-3071 vu (K=512)
    tcast_kernel<<<dim3(LATENT / 32, 1024 / 32), 256, 0, stream>>>(W_k_u, Wt_g2, LATENT, 1024);
    tcast_kernel<<<dim3(LATENT / 32, HIDDEN / 32), 256, 0, stream>>>(W_v_u, Wt_g2 + (size_t)1024 * LATENT, LATENT, HIDDEN);
    // G3 B: rows 0-1023 qu, 1024-2047 rq (K=512)
    tcast_kernel<<<dim3(LATENT / 32, 1024 / 32), 256, 0, stream>>>(W_q_u, Wt_g3, LATENT, 1024);
    tcast_kernel<<<dim3(LATENT / 32, 1024 / 32), 256, 0, stream>>>(W_rq, Wt_g3 + (size_t)1024 * LATENT, LATENT, 1024);
    tcast_kernel<<<dim3(HIDDEN / 32, HIDDEN / 32), 256, 0, stream>>>(W_o, Wt_o, HIDDEN, HIDDEN);

    // G1: xb @ [kvd|qd|rk]  (N=2048, K=2048); rope fused for rk segment -> kg hi
    mfma_gemm<1><<<dim3(2048 / 128, MROWS / 128), 256, 0, stream>>>(
        xb, Wt_g1, b_kv_d, b_q_d, b_rk, kv_d, q_d, kg, cosT, sinT, MROWS, 2048, HIDDEN);
    // G2: kv_d @ [ku|vu]  (N=3072, K=512): k1 -> kg lo, v -> vtg
    mfma_gemm<2><<<dim3(3072 / 128, MROWS / 128), 256, 0, stream>>>(
        kv_d, Wt_g2, b_k_u, b_v_u, nullptr, kg, vtg, nullptr, nullptr, nullptr, MROWS, 3072, LATENT);
    // G3: q_d @ [qu|rq]  (N=2048, K=512): q1 -> qg lo, rope(q2) -> qg hi
    mfma_gemm<3><<<dim3(2048 / 128, MROWS / 128), 256, 0, stream>>>(
        q_d, Wt_g3, b_q_u, b_rq, nullptr, qg, qg, nullptr, cosT, sinT, MROWS, 2048, LATENT);

    // attention -> attnb (1024 XCD-pinned blocks, 1 q-tile each)
    attn_mfma_kernel<<<1024, 256, 0, stream>>>(qg, kg, vtg, attnb);

    // G4: attnb @ W_o + b_o -> fp32 d_out  (N=2048, K=2048)
    mfma_gemm<4><<<dim3(2048 / 128, MROWS / 128), 256, 0, stream>>>(
        attnb, Wt_o, b_o, nullptr, nullptr, d_out, nullptr, nullptr, nullptr, nullptr, MROWS, 2048, HIDDEN);
}